// Round 9
// baseline (190.925 us; speedup 1.0000x reference)
//
#include <hip/hip_runtime.h>
#include <hip/hip_bf16.h>

typedef __attribute__((ext_vector_type(8))) short short8;
typedef __attribute__((ext_vector_type(4))) float f32x4;

constexpr int B_ = 4, S_ = 2048, D_ = 512, H_ = 8, DP_ = 64;
constexpr int M_ = B_ * S_;  // 8192 rows

__device__ __forceinline__ unsigned short f2b(float f) {
    __hip_bfloat16 h = __float2bfloat16(f);
    return *reinterpret_cast<unsigned short*>(&h);
}

__device__ __forceinline__ void gload_lds16(const unsigned short* g, unsigned short* l) {
    __builtin_amdgcn_global_load_lds((const __attribute__((address_space(1))) void*)g,
                                     (__attribute__((address_space(3))) void*)l, 16, 0, 0);
}

#define MFMA16(a, b, c) __builtin_amdgcn_mfma_f32_16x16x32_bf16((a), (b), (c), 0, 0, 0)
#define ASM_BAR() asm volatile("s_barrier" ::: "memory")

// ---------------- prep: convert_x (blocks 0..4095) U transpose_w (blocks 4096..4351) ----
// Fused to remove one dispatch gap and overlap the two independent workloads.
__global__ __launch_bounds__(256)
void prep(const float* __restrict__ x, unsigned short* __restrict__ xb,
          const float* __restrict__ w0, const float* __restrict__ w1,
          const float* __restrict__ w2, const float* __restrict__ w3,
          unsigned short* __restrict__ outw) {
    __shared__ float t[64][65];
    int bx = blockIdx.x;
    int tid = threadIdx.x;
    if (bx < 4096) {
        int i = bx * 256 + tid;   // one float4 per thread
        float4 v = ((const float4*)x)[i];
        ushort4 o;
        o.x = f2b(v.x); o.y = f2b(v.y); o.z = f2b(v.z); o.w = f2b(v.w);
        ((ushort4*)xb)[i] = o;
        return;
    }
    int b = bx - 4096;            // 256 transpose blocks
    int z = b >> 6, r = b & 63;
    int k0 = (r >> 3) * 64, n0 = (r & 7) * 64;
    const float* in = (z == 0) ? w0 : (z == 1) ? w1 : (z == 2) ? w2 : w3;
    unsigned short* out = outw + (size_t)z * D_ * D_;
    int tx = tid & 63, ty = tid >> 6;
#pragma unroll
    for (int i = 0; i < 16; i++) {
        int rr = ty * 16 + i;
        t[rr][tx] = in[(size_t)(k0 + rr) * D_ + n0 + tx];
    }
    __syncthreads();
#pragma unroll
    for (int i = 0; i < 16; i++) {
        int rr = ty * 16 + i;
        out[(size_t)(n0 + rr) * D_ + k0 + tx] = f2b(t[tx][rr]);
    }
}

// ======== merged projection GEMM: z=0 -> Q, z=1 -> K, z=2 -> V^T ========
// 128x128 / BK=64, global_load_lds staging (inverse-swizzled source), XOR-swizzled
// b128 reads, C^T fragments, LDS C-tile -> coalesced 16B stores.
__global__ __launch_bounds__(256, 3)
void gemm_qkvv(const unsigned short* __restrict__ X,
               const unsigned short* __restrict__ Wt,   // [3][512][512] transposed bf16
               unsigned short* __restrict__ QKV,        // [2][B][H][S][64]
               unsigned short* __restrict__ Vt) {       // [B][D][S]
    int z = blockIdx.z;
    int tid = threadIdx.x;
    int wave = tid >> 6, lane = tid & 63, l16 = lane & 15, quad = lane >> 4;
    int wm = (wave >> 1) * 64, wn = (wave & 1) * 64;

    int m0, n0, bb = 0;
    const unsigned short *Abase, *Bbase;
    if (z < 2) {
        m0 = blockIdx.x * 128; n0 = blockIdx.y * 128;
        Abase = X + (size_t)m0 * D_;                       // rows of X
        Bbase = Wt + (size_t)z * D_ * D_ + (size_t)n0 * D_; // rows of Wq/Wk^T
    } else {
        int idx = blockIdx.y * 64 + blockIdx.x;            // [0,256)
        bb = idx >> 6;
        int r = idx & 63;
        m0 = (r & 3) * 128;                                // d-rows of Wv^T
        n0 = (r >> 2) * 128;                               // s-cols
        Abase = Wt + 2 * (size_t)D_ * D_ + (size_t)m0 * D_;
        Bbase = X + ((size_t)bb * S_ + n0) * D_;
    }

    __shared__ __align__(16) unsigned short SM[17408];   // 34816 B union
    unsigned short (*As)[64] = reinterpret_cast<unsigned short(*)[64]>(SM);
    unsigned short (*Bs)[64] = reinterpret_cast<unsigned short(*)[64]>(SM + 8192);
    unsigned short (*Cs)[136] = reinterpret_cast<unsigned short(*)[136]>(SM);

    const int psw = l16 & 7;
    const int drow = lane >> 3;          // 0..7, row within 8-row DMA group
    const int dsw = (lane & 7) ^ drow;   // inverse-swizzled source chunk

    f32x4 acc[4][4];   // [nt][mt]  (C^T)
    const f32x4 zf = {0.f, 0.f, 0.f, 0.f};
#pragma unroll
    for (int i = 0; i < 4; i++)
#pragma unroll
        for (int j = 0; j < 4; j++) acc[i][j] = zf;

    for (int k0 = 0; k0 < D_; k0 += 64) {
        __syncthreads();
#pragma unroll
        for (int j = 0; j < 4; j++) {
            int r8 = wave * 32 + j * 8;
            gload_lds16(Abase + (size_t)(r8 + drow) * D_ + k0 + dsw * 8, &As[r8][0]);
            gload_lds16(Bbase + (size_t)(r8 + drow) * D_ + k0 + dsw * 8, &Bs[r8][0]);
        }
        __syncthreads();
#pragma unroll
        for (int h = 0; h < 2; h++) {
            short8 af[4], bf[4];
#pragma unroll
            for (int mt = 0; mt < 4; mt++)
                af[mt] = *(const short8*)&As[wm + mt * 16 + l16][((h * 4 + quad) ^ psw) * 8];
#pragma unroll
            for (int nt = 0; nt < 4; nt++)
                bf[nt] = *(const short8*)&Bs[wn + nt * 16 + l16][((h * 4 + quad) ^ psw) * 8];
#pragma unroll
            for (int nt = 0; nt < 4; nt++)
#pragma unroll
                for (int mt = 0; mt < 4; mt++)
                    acc[nt][mt] = MFMA16(bf[nt], af[mt], acc[nt][mt]);   // C^T
        }
    }
    // epilogue through LDS C-tile (lane holds 4 consecutive n)
    __syncthreads();
#pragma unroll
    for (int nt = 0; nt < 4; nt++)
#pragma unroll
        for (int mt = 0; mt < 4; mt++) {
            ushort4 pk;
            pk.x = f2b(acc[nt][mt][0]); pk.y = f2b(acc[nt][mt][1]);
            pk.z = f2b(acc[nt][mt][2]); pk.w = f2b(acc[nt][mt][3]);
            *(ushort4*)&Cs[wm + mt * 16 + l16][wn + nt * 16 + quad * 4] = pk;
        }
    __syncthreads();
    if (z < 2) {
        unsigned short* out = QKV + (size_t)z * M_ * D_;
#pragma unroll
        for (int i = 0; i < 8; i++) {
            int c = tid + i * 256;            // 2048 chunks = [128 m][16 n-chunks of 8]
            int ml = c >> 4, nch = c & 15;
            int m = m0 + ml, n = n0 + nch * 8;
            int b2 = m >> 11, ss = m & 2047, hh = n >> 6, dd = n & 63;
            *(short8*)(out + ((((size_t)b2 * H_ + hh) * S_ + ss) * DP_ + dd)) =
                *(const short8*)&Cs[ml][nch * 8];
        }
    } else {
#pragma unroll
        for (int i = 0; i < 8; i++) {
            int c = tid + i * 256;
            int ml = c >> 4, nch = c & 15;    // ml = d-row, nch*8 = s offset
            *(short8*)(Vt + ((size_t)bb * D_ + m0 + ml) * S_ + n0 + nch * 8) =
                *(const short8*)&Cs[ml][nch * 8];
        }
    }
}

// ---------------- flash attention: K AND V DMA-staged, double-buffered, counted vmcnt ----
// (byte-identical control since R6: ~72 us, MfmaUtil ~20)
__global__ __launch_bounds__(256, 4)
void flash_attn(const unsigned short* __restrict__ Qg, const unsigned short* __restrict__ Kg,
                const unsigned short* __restrict__ Vt, unsigned short* __restrict__ ctx) {
    int bid0 = blockIdx.x;
    int bid = (bid0 & 7) * 128 + (bid0 >> 3);   // XCD swizzle: 4 heads per XCD (1024 = 8*128)
    int qt = bid & 31, hh = (bid >> 5) & 7, bb = bid >> 8;
    int tid = threadIdx.x;
    int wave = tid >> 6, lane = tid & 63, l16 = lane & 15, quad = lane >> 4;
    int qh = quad >> 1, ql = quad & 1;

    size_t bh = ((size_t)bb * H_ + hh) * S_ * DP_;
    const unsigned short* Qb = Qg + bh;
    const unsigned short* Kb = Kg + bh;
    const unsigned short* Vb = Vt + bh;   // V^T head slice: 64 rows (d), 2048 cols (s)

    __shared__ __align__(16) unsigned short Kls[2][64][64];  // [buf][key s][d]
    __shared__ __align__(16) unsigned short Vls[2][64][64];  // [buf][d][key s]
    __shared__ __align__(16) unsigned short Ps[4][16][64];   // per-wave P

    const int psw = l16 & 7;
    const int drow = (lane >> 3) & 7;
    const int dsw = (lane & 7) ^ drow;

    short8 qf0, qf1;
    {
        const unsigned short* qp = Qb + (size_t)(qt * 64 + wave * 16 + l16) * DP_ + quad * 8;
        qf0 = *(const short8*)qp;
        qf1 = *(const short8*)(qp + 32);
    }

    auto stage = [&](int kv, int b) {
#pragma unroll
        for (int j = 0; j < 2; j++) {
            int r8 = (wave * 2 + j) * 8;
            int r = r8 + drow;
            gload_lds16(Kb + (size_t)(kv + r) * DP_ + dsw * 8, &Kls[b][r8][0]);
            gload_lds16(Vb + (size_t)r * S_ + kv + dsw * 8,    &Vls[b][r8][0]);
        }
    };

    stage(0, 0);
    stage(64, 1);
    asm volatile("s_waitcnt vmcnt(4)" ::: "memory");
    ASM_BAR();

    const f32x4 zf = {0.f, 0.f, 0.f, 0.f};
    f32x4 oacc[4];
#pragma unroll
    for (int i = 0; i < 4; i++) oacc[i] = zf;
    float m2 = -1e30f;
    float lrow = 0.f;
    constexpr float c1 = 0.125f * 1.44269504088896f;  // (1/sqrt(64)) * log2(e)

    int cur = 0;
    for (int t = 0; t < 32; t++) {
        __builtin_amdgcn_s_setprio(1);
        f32x4 sacc[4];
#pragma unroll
        for (int nt = 0; nt < 4; nt++) {
            const unsigned short* kr = &Kls[cur][nt * 16 + l16][0];
            short8 kf0 = *(const short8*)(kr + ((quad ^ psw) * 8));
            short8 kf1 = *(const short8*)(kr + (((quad ^ 4) ^ psw) * 8));
            f32x4 s = zf;
            s = MFMA16(kf0, qf0, s);
            s = MFMA16(kf1, qf1, s);
            sacc[nt] = s;
        }
        __builtin_amdgcn_s_setprio(0);

        float t4[4];
#pragma unroll
        for (int nt = 0; nt < 4; nt++)
            t4[nt] = fmaxf(fmaxf(sacc[nt][0], sacc[nt][1]), fmaxf(sacc[nt][2], sacc[nt][3]));
        float g = fmaxf(fmaxf(t4[0], t4[1]), fmaxf(t4[2], t4[3]));
        g = fmaxf(g, __shfl_xor(g, 16));
        g = fmaxf(g, __shfl_xor(g, 32));
        g *= c1;
        float alpha = 1.0f;
        bool need = !__all(g <= m2 + 8.0f);
        if (need) {
            float m2n = fmaxf(m2, g);
            alpha = __builtin_amdgcn_exp2f(m2 - m2n);
            m2 = m2n;
        }
        float rs = 0.f;
#pragma unroll
        for (int nt = 0; nt < 4; nt++) {
            float p0 = __builtin_amdgcn_exp2f(__builtin_fmaf(sacc[nt][0], c1, -m2));
            float p1 = __builtin_amdgcn_exp2f(__builtin_fmaf(sacc[nt][1], c1, -m2));
            float p2 = __builtin_amdgcn_exp2f(__builtin_fmaf(sacc[nt][2], c1, -m2));
            float p3 = __builtin_amdgcn_exp2f(__builtin_fmaf(sacc[nt][3], c1, -m2));
            rs += (p0 + p1) + (p2 + p3);
            ushort4 pk;
            pk.x = f2b(p0); pk.y = f2b(p1); pk.z = f2b(p2); pk.w = f2b(p3);
            int c8 = (2 * nt + qh) ^ psw;
            *(ushort4*)&Ps[wave][l16][c8 * 8 + 4 * ql] = pk;
        }
        rs += __shfl_xor(rs, 16);
        rs += __shfl_xor(rs, 32);
        lrow = alpha * lrow + rs;
        if (need) {
            float al0 = __shfl(alpha, quad * 4 + 0);
            float al1 = __shfl(alpha, quad * 4 + 1);
            float al2 = __shfl(alpha, quad * 4 + 2);
            float al3 = __shfl(alpha, quad * 4 + 3);
#pragma unroll
            for (int ot = 0; ot < 4; ot++) {
                oacc[ot][0] *= al0; oacc[ot][1] *= al1;
                oacc[ot][2] *= al2; oacc[ot][3] *= al3;
            }
        }

        __builtin_amdgcn_s_setprio(1);
#pragma unroll
        for (int kt = 0; kt < 2; kt++) {
            int pc = ((kt * 4 + quad) ^ psw) * 8;
            short8 pf = *(const short8*)&Ps[wave][l16][pc];
#pragma unroll
            for (int ot = 0; ot < 4; ot++) {
                short8 vf = *(const short8*)&Vls[cur][ot * 16 + l16][pc];
                oacc[ot] = MFMA16(pf, vf, oacc[ot]);
            }
        }
        __builtin_amdgcn_s_setprio(0);

        ASM_BAR();
        if (t < 30) {
            stage((t + 2) * 64, cur);
            asm volatile("s_waitcnt vmcnt(4)" ::: "memory");
        } else {
            asm volatile("s_waitcnt vmcnt(0)" ::: "memory");
        }
        ASM_BAR();
        cur ^= 1;
    }

    float lb0 = __shfl(lrow, quad * 4 + 0);
    float lb1 = __shfl(lrow, quad * 4 + 1);
    float lb2 = __shfl(lrow, quad * 4 + 2);
    float lb3 = __shfl(lrow, quad * 4 + 3);
    float iv0 = __builtin_amdgcn_rcpf(lb0);
    float iv1 = __builtin_amdgcn_rcpf(lb1);
    float iv2 = __builtin_amdgcn_rcpf(lb2);
    float iv3 = __builtin_amdgcn_rcpf(lb3);
#pragma unroll
    for (int ot = 0; ot < 4; ot++) {
        int srow0 = qt * 64 + wave * 16 + quad * 4;
        size_t base = ((size_t)bb * S_ + srow0) * D_ + hh * DP_ + ot * 16 + l16;
        ctx[base]          = f2b(oacc[ot][0] * iv0);
        ctx[base + D_]     = f2b(oacc[ot][1] * iv1);
        ctx[base + 2 * D_] = f2b(oacc[ot][2] * iv2);
        ctx[base + 3 * D_] = f2b(oacc[ot][3] * iv3);
    }
}

// ---------------- output projection GEMM -> fp32 scratch (direct f32x4 stores) ----------------
__global__ __launch_bounds__(256, 3)
void gemm_proj(const unsigned short* __restrict__ A,   // ctx [8192][512] bf16
               const unsigned short* __restrict__ Bt,  // Wo^T [512][512] bf16
               float* __restrict__ outf) {             // [8192][512] fp32
    int m0 = blockIdx.x * 128, n0 = blockIdx.y * 128;
    int tid = threadIdx.x;
    int wave = tid >> 6, lane = tid & 63, l16 = lane & 15, quad = lane >> 4;
    int wm = (wave >> 1) * 64, wn = (wave & 1) * 64;

    __shared__ __align__(16) unsigned short As[128][64];
    __shared__ __align__(16) unsigned short Bs[128][64];

    const int psw = l16 & 7;
    const int drow = lane >> 3;
    const int dsw = (lane & 7) ^ drow;

    f32x4 acc[4][4];   // [nt][mt]
    const f32x4 zf = {0.f, 0.f, 0.f, 0.f};
#pragma unroll
    for (int i = 0; i < 4; i++)
#pragma unroll
        for (int j = 0; j < 4; j++) acc[i][j] = zf;

    for (int k0 = 0; k0 < D_; k0 += 64) {
        __syncthreads();
#pragma unroll
        for (int j = 0; j < 4; j++) {
            int r8 = wave * 32 + j * 8;
            gload_lds16(A  + (size_t)(m0 + r8 + drow) * D_ + k0 + dsw * 8, &As[r8][0]);
            gload_lds16(Bt + (size_t)(n0 + r8 + drow) * D_ + k0 + dsw * 8, &Bs[r8][0]);
        }
        __syncthreads();
#pragma unroll
        for (int h = 0; h < 2; h++) {
            short8 af[4], bf[4];
#pragma unroll
            for (int mt = 0; mt < 4; mt++)
                af[mt] = *(const short8*)&As[wm + mt * 16 + l16][((h * 4 + quad) ^ psw) * 8];
#pragma unroll
            for (int nt = 0; nt < 4; nt++)
                bf[nt] = *(const short8*)&Bs[wn + nt * 16 + l16][((h * 4 + quad) ^ psw) * 8];
#pragma unroll
            for (int nt = 0; nt < 4; nt++)
#pragma unroll
                for (int mt = 0; mt < 4; mt++)
                    acc[nt][mt] = MFMA16(bf[nt], af[mt], acc[nt][mt]);   // C^T
        }
    }
    // epilogue: lane holds 4 consecutive n (fp32) -> direct 16B stores
#pragma unroll
    for (int nt = 0; nt < 4; nt++)
#pragma unroll
        for (int mt = 0; mt < 4; mt++) {
            int m = m0 + wm + mt * 16 + l16;
            int n = n0 + wn + nt * 16 + quad * 4;
            *(f32x4*)&outf[(size_t)m * D_ + n] = acc[nt][mt];
        }
}

// ---------------- bias + residual + LayerNorm: one row per wave, pure-shfl ----------------
__global__ __launch_bounds__(256, 8)
void ln_out(const float* __restrict__ tmp, const float* __restrict__ Xg,
            const float* __restrict__ bo, const float* __restrict__ gamma,
            const float* __restrict__ beta, float* __restrict__ outp) {
    int wave = threadIdx.x >> 6, lane = threadIdx.x & 63;
    int row = blockIdx.x * 4 + wave;
    const float4* t4 = (const float4*)(tmp + (size_t)row * D_);
    const float4* x4 = (const float4*)(Xg + (size_t)row * D_);
    const float4* b4 = (const float4*)bo;
    const float4* g4 = (const float4*)gamma;
    const float4* e4 = (const float4*)beta;
    float4* o4 = (float4*)(outp + (size_t)row * D_);

    float4 r[2];
    float sum = 0.f, sq = 0.f;
#pragma unroll
    for (int i = 0; i < 2; i++) {
        int c = lane + i * 64;
        float4 a = t4[c], x = x4[c], b = b4[c];
        r[i].x = a.x + x.x + b.x;
        r[i].y = a.y + x.y + b.y;
        r[i].z = a.z + x.z + b.z;
        r[i].w = a.w + x.w + b.w;
        sum += (r[i].x + r[i].y) + (r[i].z + r[i].w);
        sq += (r[i].x * r[i].x + r[i].y * r[i].y) + (r[i].z * r[i].z + r[i].w * r[i].w);
    }
#pragma unroll
    for (int off = 1; off < 64; off <<= 1) {
        sum += __shfl_xor(sum, off);
        sq += __shfl_xor(sq, off);
    }
    float mu = sum * (1.0f / D_);
    float var = sq * (1.0f / D_) - mu * mu;
    float rstd = rsqrtf(var + 1e-6f);
#pragma unroll
    for (int i = 0; i < 2; i++) {
        int c = lane + i * 64;
        float4 g = g4[c], e = e4[c];
        float4 o;
        o.x = (r[i].x - mu) * rstd * g.x + e.x;
        o.y = (r[i].y - mu) * rstd * g.y + e.y;
        o.z = (r[i].z - mu) * rstd * g.z + e.z;
        o.w = (r[i].w - mu) * rstd * g.w + e.w;
        o4[c] = o;
    }
}

extern "C" void kernel_launch(void* const* d_in, const int* in_sizes, int n_in,
                              void* d_out, int out_size, void* d_ws, size_t ws_size,
                              hipStream_t stream) {
    const float* x     = (const float*)d_in[0];
    const float* wq    = (const float*)d_in[1];
    const float* wk    = (const float*)d_in[2];
    const float* wv    = (const float*)d_in[3];
    const float* wo    = (const float*)d_in[4];
    const float* bo    = (const float*)d_in[5];
    const float* gamma = (const float*)d_in[6];
    const float* beta  = (const float*)d_in[7];
    float* out = (float*)d_out;

    // ws layout (bf16 elems unless noted), total 34 MB:
    //   [xb 8MB | wt 2MB | Q,K,Vt 24MB]
    //   ctx aliases xb (xb dead after the projection GEMMs). fp32 tmp aliases Q (dead after flash).
    unsigned short* xb  = (unsigned short*)d_ws;                    // 8192*512 bf16
    unsigned short* wt  = xb + (size_t)M_ * D_;                     // 4*512*512 bf16
    unsigned short* Q   = wt + 4 * D_ * D_;
    unsigned short* K   = Q + (size_t)M_ * D_;
    unsigned short* Vt  = K + (size_t)M_ * D_;                      // [B][512][2048]
    unsigned short* ctx = xb;                                       // alias: xb dead
    float* tmp = (float*)Q;                                         // alias: Q/K/Vt dead

    prep<<<dim3(4096 + 256), 256, 0, stream>>>(x, xb, wq, wk, wv, wo, wt);
    gemm_qkvv<<<dim3(64, 4, 3), 256, 0, stream>>>(xb, wt, Q, Vt);
    flash_attn<<<dim3(1024), 256, 0, stream>>>(Q, K, Vt, ctx);
    gemm_proj<<<dim3(64, 4), 256, 0, stream>>>(ctx, wt + 3 * (size_t)D_ * D_, tmp);
    ln_out<<<dim3(2048), 256, 0, stream>>>(tmp, x, bo, gamma, beta, out);
}

// Round 11
// 187.358 us; speedup vs baseline: 1.0190x; 1.0190x over previous
//
#include <hip/hip_runtime.h>
#include <hip/hip_bf16.h>

typedef __attribute__((ext_vector_type(8))) short short8;
typedef __attribute__((ext_vector_type(4))) float f32x4;

constexpr int B_ = 4, S_ = 2048, D_ = 512, H_ = 8, DP_ = 64;
constexpr int M_ = B_ * S_;  // 8192 rows

__device__ __forceinline__ unsigned short f2b(float f) {
    __hip_bfloat16 h = __float2bfloat16(f);
    return *reinterpret_cast<unsigned short*>(&h);
}

__device__ __forceinline__ void gload_lds16(const unsigned short* g, unsigned short* l) {
    __builtin_amdgcn_global_load_lds((const __attribute__((address_space(1))) void*)g,
                                     (__attribute__((address_space(3))) void*)l, 16, 0, 0);
}

#define MFMA16(a, b, c) __builtin_amdgcn_mfma_f32_16x16x32_bf16((a), (b), (c), 0, 0, 0)
#define ASM_BAR() asm volatile("s_barrier" ::: "memory")

// ---------------- prep: convert_x (blocks 0..4095) U transpose_w (blocks 4096..4351) ----
__global__ __launch_bounds__(256)
void prep(const float* __restrict__ x, unsigned short* __restrict__ xb,
          const float* __restrict__ w0, const float* __restrict__ w1,
          const float* __restrict__ w2, const float* __restrict__ w3,
          unsigned short* __restrict__ outw) {
    __shared__ float t[64][65];
    int bx = blockIdx.x;
    int tid = threadIdx.x;
    if (bx < 4096) {
        int i = bx * 256 + tid;   // one float4 per thread
        float4 v = ((const float4*)x)[i];
        ushort4 o;
        o.x = f2b(v.x); o.y = f2b(v.y); o.z = f2b(v.z); o.w = f2b(v.w);
        ((ushort4*)xb)[i] = o;
        return;
    }
    int b = bx - 4096;            // 256 transpose blocks
    int z = b >> 6, r = b & 63;
    int k0 = (r >> 3) * 64, n0 = (r & 7) * 64;
    const float* in = (z == 0) ? w0 : (z == 1) ? w1 : (z == 2) ? w2 : w3;
    unsigned short* out = outw + (size_t)z * D_ * D_;
    int tx = tid & 63, ty = tid >> 6;
#pragma unroll
    for (int i = 0; i < 16; i++) {
        int rr = ty * 16 + i;
        t[rr][tx] = in[(size_t)(k0 + rr) * D_ + n0 + tx];
    }
    __syncthreads();
#pragma unroll
    for (int i = 0; i < 16; i++) {
        int rr = ty * 16 + i;
        out[(size_t)(n0 + rr) * D_ + k0 + tx] = f2b(t[tx][rr]);
    }
}

// ======== merged projection GEMM: z=0 -> Q, z=1 -> K, z=2 -> V^T ========
__global__ __launch_bounds__(256, 3)
void gemm_qkvv(const unsigned short* __restrict__ X,
               const unsigned short* __restrict__ Wt,   // [3][512][512] transposed bf16
               unsigned short* __restrict__ QKV,        // [2][B][H][S][64]
               unsigned short* __restrict__ Vt) {       // [B][D][S]
    int z = blockIdx.z;
    int tid = threadIdx.x;
    int wave = tid >> 6, lane = tid & 63, l16 = lane & 15, quad = lane >> 4;
    int wm = (wave >> 1) * 64, wn = (wave & 1) * 64;

    int m0, n0, bb = 0;
    const unsigned short *Abase, *Bbase;
    if (z < 2) {
        m0 = blockIdx.x * 128; n0 = blockIdx.y * 128;
        Abase = X + (size_t)m0 * D_;
        Bbase = Wt + (size_t)z * D_ * D_ + (size_t)n0 * D_;
    } else {
        int idx = blockIdx.y * 64 + blockIdx.x;
        bb = idx >> 6;
        int r = idx & 63;
        m0 = (r & 3) * 128;
        n0 = (r >> 2) * 128;
        Abase = Wt + 2 * (size_t)D_ * D_ + (size_t)m0 * D_;
        Bbase = X + ((size_t)bb * S_ + n0) * D_;
    }

    __shared__ __align__(16) unsigned short SM[17408];
    unsigned short (*As)[64] = reinterpret_cast<unsigned short(*)[64]>(SM);
    unsigned short (*Bs)[64] = reinterpret_cast<unsigned short(*)[64]>(SM + 8192);
    unsigned short (*Cs)[136] = reinterpret_cast<unsigned short(*)[136]>(SM);

    const int psw = l16 & 7;
    const int drow = lane >> 3;
    const int dsw = (lane & 7) ^ drow;

    f32x4 acc[4][4];   // [nt][mt]  (C^T)
    const f32x4 zf = {0.f, 0.f, 0.f, 0.f};
#pragma unroll
    for (int i = 0; i < 4; i++)
#pragma unroll
        for (int j = 0; j < 4; j++) acc[i][j] = zf;

    for (int k0 = 0; k0 < D_; k0 += 64) {
        __syncthreads();
#pragma unroll
        for (int j = 0; j < 4; j++) {
            int r8 = wave * 32 + j * 8;
            gload_lds16(Abase + (size_t)(r8 + drow) * D_ + k0 + dsw * 8, &As[r8][0]);
            gload_lds16(Bbase + (size_t)(r8 + drow) * D_ + k0 + dsw * 8, &Bs[r8][0]);
        }
        __syncthreads();
#pragma unroll
        for (int h = 0; h < 2; h++) {
            short8 af[4], bf[4];
#pragma unroll
            for (int mt = 0; mt < 4; mt++)
                af[mt] = *(const short8*)&As[wm + mt * 16 + l16][((h * 4 + quad) ^ psw) * 8];
#pragma unroll
            for (int nt = 0; nt < 4; nt++)
                bf[nt] = *(const short8*)&Bs[wn + nt * 16 + l16][((h * 4 + quad) ^ psw) * 8];
#pragma unroll
            for (int nt = 0; nt < 4; nt++)
#pragma unroll
                for (int mt = 0; mt < 4; mt++)
                    acc[nt][mt] = MFMA16(bf[nt], af[mt], acc[nt][mt]);   // C^T
        }
    }
    __syncthreads();
#pragma unroll
    for (int nt = 0; nt < 4; nt++)
#pragma unroll
        for (int mt = 0; mt < 4; mt++) {
            ushort4 pk;
            pk.x = f2b(acc[nt][mt][0]); pk.y = f2b(acc[nt][mt][1]);
            pk.z = f2b(acc[nt][mt][2]); pk.w = f2b(acc[nt][mt][3]);
            *(ushort4*)&Cs[wm + mt * 16 + l16][wn + nt * 16 + quad * 4] = pk;
        }
    __syncthreads();
    if (z < 2) {
        unsigned short* out = QKV + (size_t)z * M_ * D_;
#pragma unroll
        for (int i = 0; i < 8; i++) {
            int c = tid + i * 256;
            int ml = c >> 4, nch = c & 15;
            int m = m0 + ml, n = n0 + nch * 8;
            int b2 = m >> 11, ss = m & 2047, hh = n >> 6, dd = n & 63;
            *(short8*)(out + ((((size_t)b2 * H_ + hh) * S_ + ss) * DP_ + dd)) =
                *(const short8*)&Cs[ml][nch * 8];
        }
    } else {
#pragma unroll
        for (int i = 0; i < 8; i++) {
            int c = tid + i * 256;
            int ml = c >> 4, nch = c & 15;
            *(short8*)(Vt + ((size_t)bb * D_ + m0 + ml) * S_ + n0 + nch * 8) =
                *(const short8*)&Cs[ml][nch * 8];
        }
    }
}

// ---------------- flash attention: 32 q-rows per wave (LDS-BW fix) ----------------
// K/V fragment LDS reads are q-count-independent -> doubling q-rows per wave halves
// LDS bytes per MFMA-FLOP (12.6 -> 7.2 MB/CU). 512 blocks, DMA double-buffer +
// counted vmcnt unchanged from the verified R6 structure.
__global__ __launch_bounds__(256, 3)
void flash_attn(const unsigned short* __restrict__ Qg, const unsigned short* __restrict__ Kg,
                const unsigned short* __restrict__ Vt, unsigned short* __restrict__ ctx) {
    int bid0 = blockIdx.x;
    int bid = (bid0 & 7) * 64 + (bid0 >> 3);   // XCD swizzle (512 = 8*64, bijective)
    int qt = bid & 15, hh = (bid >> 4) & 7, bb = bid >> 7;
    int tid = threadIdx.x;
    int wave = tid >> 6, lane = tid & 63, l16 = lane & 15, quad = lane >> 4;
    int qh = quad >> 1, ql = quad & 1;

    size_t bh = ((size_t)bb * H_ + hh) * S_ * DP_;
    const unsigned short* Qb = Qg + bh;
    const unsigned short* Kb = Kg + bh;
    const unsigned short* Vb = Vt + bh;   // V^T head slice: 64 rows (d), 2048 cols (s)

    __shared__ __align__(16) unsigned short Kls[2][64][64];  // [buf][key s][d]
    __shared__ __align__(16) unsigned short Vls[2][64][64];  // [buf][d][key s]
    __shared__ __align__(16) unsigned short Ps[4][32][64];   // per-wave P (32 q-rows)

    const int psw = l16 & 7;
    const int drow = (lane >> 3) & 7;
    const int dsw = (lane & 7) ^ drow;

    // Q: 32 rows per wave, two 16-row groups A/B
    short8 qa0, qa1, qb0, qb1;
    {
        const unsigned short* qp = Qb + (size_t)(qt * 128 + wave * 32 + l16) * DP_ + quad * 8;
        qa0 = *(const short8*)qp;
        qa1 = *(const short8*)(qp + 32);
        qb0 = *(const short8*)(qp + 16 * DP_);
        qb1 = *(const short8*)(qp + 16 * DP_ + 32);
    }

    auto stage = [&](int kv, int b) {
#pragma unroll
        for (int j = 0; j < 2; j++) {
            int r8 = (wave * 2 + j) * 8;
            int r = r8 + drow;
            gload_lds16(Kb + (size_t)(kv + r) * DP_ + dsw * 8, &Kls[b][r8][0]);
            gload_lds16(Vb + (size_t)r * S_ + kv + dsw * 8,    &Vls[b][r8][0]);
        }
    };

    stage(0, 0);
    stage(64, 1);
    asm volatile("s_waitcnt vmcnt(4)" ::: "memory");
    ASM_BAR();

    const f32x4 zf = {0.f, 0.f, 0.f, 0.f};
    f32x4 oa[4], ob[4];
#pragma unroll
    for (int i = 0; i < 4; i++) { oa[i] = zf; ob[i] = zf; }
    float m2a = -1e30f, m2b = -1e30f;
    float lsa = 0.f, lsb = 0.f;
    constexpr float c1 = 0.125f * 1.44269504088896f;  // (1/sqrt(64)) * log2(e)

    int cur = 0;
    for (int t = 0; t < 32; t++) {
        // (1) S^T = K Q^T for both q-groups; K fragments read ONCE, used twice
        __builtin_amdgcn_s_setprio(1);
        f32x4 sa[4], sb[4];
#pragma unroll
        for (int nt = 0; nt < 4; nt++) {
            const unsigned short* kr = &Kls[cur][nt * 16 + l16][0];
            short8 kf0 = *(const short8*)(kr + ((quad ^ psw) * 8));
            short8 kf1 = *(const short8*)(kr + (((quad ^ 4) ^ psw) * 8));
            f32x4 s = zf;
            s = MFMA16(kf0, qa0, s);
            s = MFMA16(kf1, qa1, s);
            sa[nt] = s;
            s = zf;
            s = MFMA16(kf0, qb0, s);
            s = MFMA16(kf1, qb1, s);
            sb[nt] = s;
        }
        __builtin_amdgcn_s_setprio(0);

        // (2) defer-max online softmax, two lane-local rows
        float ga, gb;
        {
            float ta[4], tb[4];
#pragma unroll
            for (int nt = 0; nt < 4; nt++) {
                ta[nt] = fmaxf(fmaxf(sa[nt][0], sa[nt][1]), fmaxf(sa[nt][2], sa[nt][3]));
                tb[nt] = fmaxf(fmaxf(sb[nt][0], sb[nt][1]), fmaxf(sb[nt][2], sb[nt][3]));
            }
            ga = fmaxf(fmaxf(ta[0], ta[1]), fmaxf(ta[2], ta[3]));
            gb = fmaxf(fmaxf(tb[0], tb[1]), fmaxf(tb[2], tb[3]));
        }
        ga = fmaxf(ga, __shfl_xor(ga, 16));
        ga = fmaxf(ga, __shfl_xor(ga, 32));
        gb = fmaxf(gb, __shfl_xor(gb, 16));
        gb = fmaxf(gb, __shfl_xor(gb, 32));
        ga *= c1; gb *= c1;
        float ala = 1.0f, alb = 1.0f;
        bool need = !__all((ga <= m2a + 8.0f) && (gb <= m2b + 8.0f));
        if (need) {
            float na = fmaxf(m2a, ga), nb = fmaxf(m2b, gb);
            ala = __builtin_amdgcn_exp2f(m2a - na);
            alb = __builtin_amdgcn_exp2f(m2b - nb);
            m2a = na; m2b = nb;
        }
        float rsa = 0.f, rsb = 0.f;
#pragma unroll
        for (int nt = 0; nt < 4; nt++) {
            float a0 = __builtin_amdgcn_exp2f(__builtin_fmaf(sa[nt][0], c1, -m2a));
            float a1 = __builtin_amdgcn_exp2f(__builtin_fmaf(sa[nt][1], c1, -m2a));
            float a2 = __builtin_amdgcn_exp2f(__builtin_fmaf(sa[nt][2], c1, -m2a));
            float a3 = __builtin_amdgcn_exp2f(__builtin_fmaf(sa[nt][3], c1, -m2a));
            rsa += (a0 + a1) + (a2 + a3);
            ushort4 pk;
            pk.x = f2b(a0); pk.y = f2b(a1); pk.z = f2b(a2); pk.w = f2b(a3);
            int c8 = (2 * nt + qh) ^ psw;
            *(ushort4*)&Ps[wave][l16][c8 * 8 + 4 * ql] = pk;
            float b0 = __builtin_amdgcn_exp2f(__builtin_fmaf(sb[nt][0], c1, -m2b));
            float b1 = __builtin_amdgcn_exp2f(__builtin_fmaf(sb[nt][1], c1, -m2b));
            float b2 = __builtin_amdgcn_exp2f(__builtin_fmaf(sb[nt][2], c1, -m2b));
            float b3 = __builtin_amdgcn_exp2f(__builtin_fmaf(sb[nt][3], c1, -m2b));
            rsb += (b0 + b1) + (b2 + b3);
            pk.x = f2b(b0); pk.y = f2b(b1); pk.z = f2b(b2); pk.w = f2b(b3);
            *(ushort4*)&Ps[wave][16 + l16][c8 * 8 + 4 * ql] = pk;
        }
        rsa += __shfl_xor(rsa, 16);
        rsa += __shfl_xor(rsa, 32);
        rsb += __shfl_xor(rsb, 16);
        rsb += __shfl_xor(rsb, 32);
        lsa = ala * lsa + rsa;
        lsb = alb * lsb + rsb;
        if (need) {
            float a0 = __shfl(ala, quad * 4 + 0), a1 = __shfl(ala, quad * 4 + 1);
            float a2 = __shfl(ala, quad * 4 + 2), a3 = __shfl(ala, quad * 4 + 3);
            float b0 = __shfl(alb, quad * 4 + 0), b1 = __shfl(alb, quad * 4 + 1);
            float b2 = __shfl(alb, quad * 4 + 2), b3 = __shfl(alb, quad * 4 + 3);
#pragma unroll
            for (int ot = 0; ot < 4; ot++) {
                oa[ot][0] *= a0; oa[ot][1] *= a1; oa[ot][2] *= a2; oa[ot][3] *= a3;
                ob[ot][0] *= b0; ob[ot][1] *= b1; ob[ot][2] *= b2; ob[ot][3] *= b3;
            }
        }

        // (3) O += P V : V fragments read ONCE, used for both q-groups
        __builtin_amdgcn_s_setprio(1);
#pragma unroll
        for (int kt = 0; kt < 2; kt++) {
            int pc = ((kt * 4 + quad) ^ psw) * 8;
            short8 pfA = *(const short8*)&Ps[wave][l16][pc];
            short8 pfB = *(const short8*)&Ps[wave][16 + l16][pc];
#pragma unroll
            for (int ot = 0; ot < 4; ot++) {
                short8 vf = *(const short8*)&Vls[cur][ot * 16 + l16][pc];
                oa[ot] = MFMA16(pfA, vf, oa[ot]);
                ob[ot] = MFMA16(pfB, vf, ob[ot]);
            }
        }
        __builtin_amdgcn_s_setprio(0);

        ASM_BAR();
        if (t < 30) {
            stage((t + 2) * 64, cur);
            asm volatile("s_waitcnt vmcnt(4)" ::: "memory");
        } else {
            asm volatile("s_waitcnt vmcnt(0)" ::: "memory");
        }
        ASM_BAR();
        cur ^= 1;
    }

    // epilogue: normalize both groups, merge heads into [B][S][512]
    float la0 = __shfl(lsa, quad * 4 + 0), la1 = __shfl(lsa, quad * 4 + 1);
    float la2 = __shfl(lsa, quad * 4 + 2), la3 = __shfl(lsa, quad * 4 + 3);
    float lb0 = __shfl(lsb, quad * 4 + 0), lb1 = __shfl(lsb, quad * 4 + 1);
    float lb2 = __shfl(lsb, quad * 4 + 2), lb3 = __shfl(lsb, quad * 4 + 3);
    float ia0 = __builtin_amdgcn_rcpf(la0), ia1 = __builtin_amdgcn_rcpf(la1);
    float ia2 = __builtin_amdgcn_rcpf(la2), ia3 = __builtin_amdgcn_rcpf(la3);
    float ib0 = __builtin_amdgcn_rcpf(lb0), ib1 = __builtin_amdgcn_rcpf(lb1);
    float ib2 = __builtin_amdgcn_rcpf(lb2), ib3 = __builtin_amdgcn_rcpf(lb3);
    int srow0 = qt * 128 + wave * 32 + quad * 4;
#pragma unroll
    for (int ot = 0; ot < 4; ot++) {
        size_t base = ((size_t)bb * S_ + srow0) * D_ + hh * DP_ + ot * 16 + l16;
        ctx[base]          = f2b(oa[ot][0] * ia0);
        ctx[base + D_]     = f2b(oa[ot][1] * ia1);
        ctx[base + 2 * D_] = f2b(oa[ot][2] * ia2);
        ctx[base + 3 * D_] = f2b(oa[ot][3] * ia3);
        size_t baseB = base + (size_t)16 * D_;
        ctx[baseB]          = f2b(ob[ot][0] * ib0);
        ctx[baseB + D_]     = f2b(ob[ot][1] * ib1);
        ctx[baseB + 2 * D_] = f2b(ob[ot][2] * ib2);
        ctx[baseB + 3 * D_] = f2b(ob[ot][3] * ib3);
    }
}

// ---------------- output projection GEMM -> fp32 scratch ----------------
__global__ __launch_bounds__(256, 3)
void gemm_proj(const unsigned short* __restrict__ A,   // ctx [8192][512] bf16
               const unsigned short* __restrict__ Bt,  // Wo^T [512][512] bf16
               float* __restrict__ outf) {             // [8192][512] fp32
    int m0 = blockIdx.x * 128, n0 = blockIdx.y * 128;
    int tid = threadIdx.x;
    int wave = tid >> 6, lane = tid & 63, l16 = lane & 15, quad = lane >> 4;
    int wm = (wave >> 1) * 64, wn = (wave & 1) * 64;

    __shared__ __align__(16) unsigned short As[128][64];
    __shared__ __align__(16) unsigned short Bs[128][64];

    const int psw = l16 & 7;
    const int drow = lane >> 3;
    const int dsw = (lane & 7) ^ drow;

    f32x4 acc[4][4];   // [nt][mt]
    const f32x4 zf = {0.f, 0.f, 0.f, 0.f};
#pragma unroll
    for (int i = 0; i < 4; i++)
#pragma unroll
        for (int j = 0; j < 4; j++) acc[i][j] = zf;

    for (int k0 = 0; k0 < D_; k0 += 64) {
        __syncthreads();
#pragma unroll
        for (int j = 0; j < 4; j++) {
            int r8 = wave * 32 + j * 8;
            gload_lds16(A  + (size_t)(m0 + r8 + drow) * D_ + k0 + dsw * 8, &As[r8][0]);
            gload_lds16(Bt + (size_t)(n0 + r8 + drow) * D_ + k0 + dsw * 8, &Bs[r8][0]);
        }
        __syncthreads();
#pragma unroll
        for (int h = 0; h < 2; h++) {
            short8 af[4], bf[4];
#pragma unroll
            for (int mt = 0; mt < 4; mt++)
                af[mt] = *(const short8*)&As[wm + mt * 16 + l16][((h * 4 + quad) ^ psw) * 8];
#pragma unroll
            for (int nt = 0; nt < 4; nt++)
                bf[nt] = *(const short8*)&Bs[wn + nt * 16 + l16][((h * 4 + quad) ^ psw) * 8];
#pragma unroll
            for (int nt = 0; nt < 4; nt++)
#pragma unroll
                for (int mt = 0; mt < 4; mt++)
                    acc[nt][mt] = MFMA16(bf[nt], af[mt], acc[nt][mt]);   // C^T
        }
    }
#pragma unroll
    for (int nt = 0; nt < 4; nt++)
#pragma unroll
        for (int mt = 0; mt < 4; mt++) {
            int m = m0 + wm + mt * 16 + l16;
            int n = n0 + wn + nt * 16 + quad * 4;
            *(f32x4*)&outf[(size_t)m * D_ + n] = acc[nt][mt];
        }
}

// ---------------- bias + residual + LayerNorm: one row per wave, pure-shfl ----------------
__global__ __launch_bounds__(256, 8)
void ln_out(const float* __restrict__ tmp, const float* __restrict__ Xg,
            const float* __restrict__ bo, const float* __restrict__ gamma,
            const float* __restrict__ beta, float* __restrict__ outp) {
    int wave = threadIdx.x >> 6, lane = threadIdx.x & 63;
    int row = blockIdx.x * 4 + wave;
    const float4* t4 = (const float4*)(tmp + (size_t)row * D_);
    const float4* x4 = (const float4*)(Xg + (size_t)row * D_);
    const float4* b4 = (const float4*)bo;
    const float4* g4 = (const float4*)gamma;
    const float4* e4 = (const float4*)beta;
    float4* o4 = (float4*)(outp + (size_t)row * D_);

    float4 r[2];
    float sum = 0.f, sq = 0.f;
#pragma unroll
    for (int i = 0; i < 2; i++) {
        int c = lane + i * 64;
        float4 a = t4[c], x = x4[c], b = b4[c];
        r[i].x = a.x + x.x + b.x;
        r[i].y = a.y + x.y + b.y;
        r[i].z = a.z + x.z + b.z;
        r[i].w = a.w + x.w + b.w;
        sum += (r[i].x + r[i].y) + (r[i].z + r[i].w);
        sq += (r[i].x * r[i].x + r[i].y * r[i].y) + (r[i].z * r[i].z + r[i].w * r[i].w);
    }
#pragma unroll
    for (int off = 1; off < 64; off <<= 1) {
        sum += __shfl_xor(sum, off);
        sq += __shfl_xor(sq, off);
    }
    float mu = sum * (1.0f / D_);
    float var = sq * (1.0f / D_) - mu * mu;
    float rstd = rsqrtf(var + 1e-6f);
#pragma unroll
    for (int i = 0; i < 2; i++) {
        int c = lane + i * 64;
        float4 g = g4[c], e = e4[c];
        float4 o;
        o.x = (r[i].x - mu) * rstd * g.x + e.x;
        o.y = (r[i].y - mu) * rstd * g.y + e.y;
        o.z = (r[i].z - mu) * rstd * g.z + e.z;
        o.w = (r[i].w - mu) * rstd * g.w + e.w;
        o4[c] = o;
    }
}

extern "C" void kernel_launch(void* const* d_in, const int* in_sizes, int n_in,
                              void* d_out, int out_size, void* d_ws, size_t ws_size,
                              hipStream_t stream) {
    const float* x     = (const float*)d_in[0];
    const float* wq    = (const float*)d_in[1];
    const float* wk    = (const float*)d_in[2];
    const float* wv    = (const float*)d_in[3];
    const float* wo    = (const float*)d_in[4];
    const float* bo    = (const float*)d_in[5];
    const float* gamma = (const float*)d_in[6];
    const float* beta  = (const float*)d_in[7];
    float* out = (float*)d_out;

    // ws layout (bf16 elems unless noted), total 34 MB:
    //   [xb 8MB | wt 2MB | Q,K,Vt 24MB]
    //   ctx aliases xb (xb dead after the projection GEMMs). fp32 tmp aliases Q (dead after flash).
    unsigned short* xb  = (unsigned short*)d_ws;                    // 8192*512 bf16
    unsigned short* wt  = xb + (size_t)M_ * D_;                     // 4*512*512 bf16
    unsigned short* Q   = wt + 4 * D_ * D_;
    unsigned short* K   = Q + (size_t)M_ * D_;
    unsigned short* Vt  = K + (size_t)M_ * D_;                      // [B][512][2048]
    unsigned short* ctx = xb;                                       // alias: xb dead
    float* tmp = (float*)Q;                                         // alias: Q/K/Vt dead

    prep<<<dim3(4096 + 256), 256, 0, stream>>>(x, xb, wq, wk, wv, wo, wt);
    gemm_qkvv<<<dim3(64, 4, 3), 256, 0, stream>>>(xb, wt, Q, Vt);
    flash_attn<<<dim3(512), 256, 0, stream>>>(Q, K, Vt, ctx);
    gemm_proj<<<dim3(64, 4), 256, 0, stream>>>(ctx, wt + 3 * (size_t)D_ * D_, tmp);
    ln_out<<<dim3(2048), 256, 0, stream>>>(tmp, x, bo, gamma, beta, out);
}

// Round 14
// 178.153 us; speedup vs baseline: 1.0717x; 1.0517x over previous
//
#include <hip/hip_runtime.h>
#include <hip/hip_bf16.h>

typedef __attribute__((ext_vector_type(8))) short short8;
typedef __attribute__((ext_vector_type(4))) float f32x4;

constexpr int B_ = 4, S_ = 2048, D_ = 512, H_ = 8, DP_ = 64;
constexpr int M_ = B_ * S_;  // 8192 rows

__device__ __forceinline__ unsigned short f2b(float f) {
    __hip_bfloat16 h = __float2bfloat16(f);
    return *reinterpret_cast<unsigned short*>(&h);
}

__device__ __forceinline__ void gload_lds16(const unsigned short* g, unsigned short* l) {
    __builtin_amdgcn_global_load_lds((const __attribute__((address_space(1))) void*)g,
                                     (__attribute__((address_space(3))) void*)l, 16, 0, 0);
}

#define MFMA16(a, b, c) __builtin_amdgcn_mfma_f32_16x16x32_bf16((a), (b), (c), 0, 0, 0)
#define ASM_BAR() asm volatile("s_barrier" ::: "memory")

// ---------------- prep: convert_x (blocks 0..4095) U transpose_w (blocks 4096..4351) ----
__global__ __launch_bounds__(256)
void prep(const float* __restrict__ x, unsigned short* __restrict__ xb,
          const float* __restrict__ w0, const float* __restrict__ w1,
          const float* __restrict__ w2, const float* __restrict__ w3,
          unsigned short* __restrict__ outw) {
    __shared__ float t[64][65];
    int bx = blockIdx.x;
    int tid = threadIdx.x;
    if (bx < 4096) {
        int i = bx * 256 + tid;   // one float4 per thread
        float4 v = ((const float4*)x)[i];
        ushort4 o;
        o.x = f2b(v.x); o.y = f2b(v.y); o.z = f2b(v.z); o.w = f2b(v.w);
        ((ushort4*)xb)[i] = o;
        return;
    }
    int b = bx - 4096;            // 256 transpose blocks
    int z = b >> 6, r = b & 63;
    int k0 = (r >> 3) * 64, n0 = (r & 7) * 64;
    const float* in = (z == 0) ? w0 : (z == 1) ? w1 : (z == 2) ? w2 : w3;
    unsigned short* out = outw + (size_t)z * D_ * D_;
    int tx = tid & 63, ty = tid >> 6;
#pragma unroll
    for (int i = 0; i < 16; i++) {
        int rr = ty * 16 + i;
        t[rr][tx] = in[(size_t)(k0 + rr) * D_ + n0 + tx];
    }
    __syncthreads();
#pragma unroll
    for (int i = 0; i < 16; i++) {
        int rr = ty * 16 + i;
        out[(size_t)(n0 + rr) * D_ + k0 + tx] = f2b(t[tx][rr]);
    }
}

// ======== merged projection GEMM: z=0 -> Q, z=1 -> K, z=2 -> V^T ========
// Double-buffered K-loop, counted vmcnt (R6 pipeline). 8 tiles of BK=64 = 512.
__global__ __launch_bounds__(256, 2)
void gemm_qkvv(const unsigned short* __restrict__ X,
               const unsigned short* __restrict__ Wt,   // [3][512][512] transposed bf16
               unsigned short* __restrict__ QKV,        // [2][B][H][S][64]
               unsigned short* __restrict__ Vt) {       // [B][D][S]
    int z = blockIdx.z;
    int tid = threadIdx.x;
    int wave = tid >> 6, lane = tid & 63, l16 = lane & 15, quad = lane >> 4;
    int wm = (wave >> 1) * 64, wn = (wave & 1) * 64;

    int m0, n0, bb = 0;
    const unsigned short *Abase, *Bbase;
    if (z < 2) {
        m0 = blockIdx.x * 128; n0 = blockIdx.y * 128;
        Abase = X + (size_t)m0 * D_;
        Bbase = Wt + (size_t)z * D_ * D_ + (size_t)n0 * D_;
    } else {
        int idx = blockIdx.y * 64 + blockIdx.x;
        bb = idx >> 6;
        int r = idx & 63;
        m0 = (r & 3) * 128;
        n0 = (r >> 2) * 128;
        Abase = Wt + 2 * (size_t)D_ * D_ + (size_t)m0 * D_;
        Bbase = X + ((size_t)bb * S_ + n0) * D_;
    }

    // layout: [As0 (8K) | Bs0 (8K) | As1 (8K) | Bs1 (8K)] shorts = 64KB
    __shared__ __align__(16) unsigned short SM[32768];
    unsigned short (*Cs)[136] = reinterpret_cast<unsigned short(*)[136]>(SM);

    const int psw = l16 & 7;
    const int drow = lane >> 3;
    const int dsw = (lane & 7) ^ drow;

    auto stage = [&](int t, int b) {
        int k0 = t * 64;
        unsigned short* As = SM + b * 16384;
        unsigned short* Bs = SM + b * 16384 + 8192;
#pragma unroll
        for (int j = 0; j < 4; j++) {
            int r8 = wave * 32 + j * 8;
            gload_lds16(Abase + (size_t)(r8 + drow) * D_ + k0 + dsw * 8, As + r8 * 64);
            gload_lds16(Bbase + (size_t)(r8 + drow) * D_ + k0 + dsw * 8, Bs + r8 * 64);
        }
    };

    f32x4 acc[4][4];   // [nt][mt]  (C^T)
    const f32x4 zf = {0.f, 0.f, 0.f, 0.f};
#pragma unroll
    for (int i = 0; i < 4; i++)
#pragma unroll
        for (int j = 0; j < 4; j++) acc[i][j] = zf;

    stage(0, 0);
    stage(1, 1);
    asm volatile("s_waitcnt vmcnt(8)" ::: "memory");
    ASM_BAR();

    for (int t = 0; t < 8; t++) {
        int b = t & 1;
        const unsigned short* As = SM + b * 16384;
        const unsigned short* Bs = SM + b * 16384 + 8192;
#pragma unroll
        for (int h = 0; h < 2; h++) {
            short8 af[4], bf[4];
#pragma unroll
            for (int mt = 0; mt < 4; mt++)
                af[mt] = *(const short8*)(As + (wm + mt * 16 + l16) * 64 + ((h * 4 + quad) ^ psw) * 8);
#pragma unroll
            for (int nt = 0; nt < 4; nt++)
                bf[nt] = *(const short8*)(Bs + (wn + nt * 16 + l16) * 64 + ((h * 4 + quad) ^ psw) * 8);
#pragma unroll
            for (int nt = 0; nt < 4; nt++)
#pragma unroll
                for (int mt = 0; mt < 4; mt++)
                    acc[nt][mt] = MFMA16(bf[nt], af[mt], acc[nt][mt]);   // C^T
        }
        if (t < 7) {
            ASM_BAR();
            if (t < 6) {
                stage(t + 2, b);
                asm volatile("s_waitcnt vmcnt(8)" ::: "memory");
            } else {
                asm volatile("s_waitcnt vmcnt(0)" ::: "memory");
            }
            ASM_BAR();
        }
    }
    // epilogue through LDS C-tile (lane holds 4 consecutive n)
    __syncthreads();
#pragma unroll
    for (int nt = 0; nt < 4; nt++)
#pragma unroll
        for (int mt = 0; mt < 4; mt++) {
            ushort4 pk;
            pk.x = f2b(acc[nt][mt][0]); pk.y = f2b(acc[nt][mt][1]);
            pk.z = f2b(acc[nt][mt][2]); pk.w = f2b(acc[nt][mt][3]);
            *(ushort4*)&Cs[wm + mt * 16 + l16][wn + nt * 16 + quad * 4] = pk;
        }
    __syncthreads();
    if (z < 2) {
        unsigned short* out = QKV + (size_t)z * M_ * D_;
#pragma unroll
        for (int i = 0; i < 8; i++) {
            int c = tid + i * 256;
            int ml = c >> 4, nch = c & 15;
            int m = m0 + ml, n = n0 + nch * 8;
            int b2 = m >> 11, ss = m & 2047, hh = n >> 6, dd = n & 63;
            *(short8*)(out + ((((size_t)b2 * H_ + hh) * S_ + ss) * DP_ + dd)) =
                *(const short8*)&Cs[ml][nch * 8];
        }
    } else {
#pragma unroll
        for (int i = 0; i < 8; i++) {
            int c = tid + i * 256;
            int ml = c >> 4, nch = c & 15;
            *(short8*)(Vt + ((size_t)bb * D_ + m0 + ml) * S_ + n0 + nch * 8) =
                *(const short8*)&Cs[ml][nch * 8];
        }
    }
}

// ---------------- flash attention: 32 q-rows per wave (unchanged R11 control: 66.8 us) ----
__global__ __launch_bounds__(256, 3)
void flash_attn(const unsigned short* __restrict__ Qg, const unsigned short* __restrict__ Kg,
                const unsigned short* __restrict__ Vt, unsigned short* __restrict__ ctx) {
    int bid0 = blockIdx.x;
    int bid = (bid0 & 7) * 64 + (bid0 >> 3);   // XCD swizzle (512 = 8*64, bijective)
    int qt = bid & 15, hh = (bid >> 4) & 7, bb = bid >> 7;
    int tid = threadIdx.x;
    int wave = tid >> 6, lane = tid & 63, l16 = lane & 15, quad = lane >> 4;
    int qh = quad >> 1, ql = quad & 1;

    size_t bh = ((size_t)bb * H_ + hh) * S_ * DP_;
    const unsigned short* Qb = Qg + bh;
    const unsigned short* Kb = Kg + bh;
    const unsigned short* Vb = Vt + bh;   // V^T head slice: 64 rows (d), 2048 cols (s)

    __shared__ __align__(16) unsigned short Kls[2][64][64];  // [buf][key s][d]
    __shared__ __align__(16) unsigned short Vls[2][64][64];  // [buf][d][key s]
    __shared__ __align__(16) unsigned short Ps[4][32][64];   // per-wave P (32 q-rows)

    const int psw = l16 & 7;
    const int drow = (lane >> 3) & 7;
    const int dsw = (lane & 7) ^ drow;

    // Q: 32 rows per wave, two 16-row groups A/B
    short8 qa0, qa1, qb0, qb1;
    {
        const unsigned short* qp = Qb + (size_t)(qt * 128 + wave * 32 + l16) * DP_ + quad * 8;
        qa0 = *(const short8*)qp;
        qa1 = *(const short8*)(qp + 32);
        qb0 = *(const short8*)(qp + 16 * DP_);
        qb1 = *(const short8*)(qp + 16 * DP_ + 32);
    }

    auto stage = [&](int kv, int b) {
#pragma unroll
        for (int j = 0; j < 2; j++) {
            int r8 = (wave * 2 + j) * 8;
            int r = r8 + drow;
            gload_lds16(Kb + (size_t)(kv + r) * DP_ + dsw * 8, &Kls[b][r8][0]);
            gload_lds16(Vb + (size_t)r * S_ + kv + dsw * 8,    &Vls[b][r8][0]);
        }
    };

    stage(0, 0);
    stage(64, 1);
    asm volatile("s_waitcnt vmcnt(4)" ::: "memory");
    ASM_BAR();

    const f32x4 zf = {0.f, 0.f, 0.f, 0.f};
    f32x4 oa[4], ob[4];
#pragma unroll
    for (int i = 0; i < 4; i++) { oa[i] = zf; ob[i] = zf; }
    float m2a = -1e30f, m2b = -1e30f;
    float lsa = 0.f, lsb = 0.f;
    constexpr float c1 = 0.125f * 1.44269504088896f;  // (1/sqrt(64)) * log2(e)

    int cur = 0;
    for (int t = 0; t < 32; t++) {
        // (1) S^T = K Q^T for both q-groups; K fragments read ONCE, used twice
        __builtin_amdgcn_s_setprio(1);
        f32x4 sa[4], sb[4];
#pragma unroll
        for (int nt = 0; nt < 4; nt++) {
            const unsigned short* kr = &Kls[cur][nt * 16 + l16][0];
            short8 kf0 = *(const short8*)(kr + ((quad ^ psw) * 8));
            short8 kf1 = *(const short8*)(kr + (((quad ^ 4) ^ psw) * 8));
            f32x4 s = zf;
            s = MFMA16(kf0, qa0, s);
            s = MFMA16(kf1, qa1, s);
            sa[nt] = s;
            s = zf;
            s = MFMA16(kf0, qb0, s);
            s = MFMA16(kf1, qb1, s);
            sb[nt] = s;
        }
        __builtin_amdgcn_s_setprio(0);

        // (2) defer-max online softmax, two lane-local rows
        float ga, gb;
        {
            float ta[4], tb[4];
#pragma unroll
            for (int nt = 0; nt < 4; nt++) {
                ta[nt] = fmaxf(fmaxf(sa[nt][0], sa[nt][1]), fmaxf(sa[nt][2], sa[nt][3]));
                tb[nt] = fmaxf(fmaxf(sb[nt][0], sb[nt][1]), fmaxf(sb[nt][2], sb[nt][3]));
            }
            ga = fmaxf(fmaxf(ta[0], ta[1]), fmaxf(ta[2], ta[3]));
            gb = fmaxf(fmaxf(tb[0], tb[1]), fmaxf(tb[2], tb[3]));
        }
        ga = fmaxf(ga, __shfl_xor(ga, 16));
        ga = fmaxf(ga, __shfl_xor(ga, 32));
        gb = fmaxf(gb, __shfl_xor(gb, 16));
        gb = fmaxf(gb, __shfl_xor(gb, 32));
        ga *= c1; gb *= c1;
        float ala = 1.0f, alb = 1.0f;
        bool need = !__all((ga <= m2a + 8.0f) && (gb <= m2b + 8.0f));
        if (need) {
            float na = fmaxf(m2a, ga), nb = fmaxf(m2b, gb);
            ala = __builtin_amdgcn_exp2f(m2a - na);
            alb = __builtin_amdgcn_exp2f(m2b - nb);
            m2a = na; m2b = nb;
        }
        float rsa = 0.f, rsb = 0.f;
#pragma unroll
        for (int nt = 0; nt < 4; nt++) {
            float a0 = __builtin_amdgcn_exp2f(__builtin_fmaf(sa[nt][0], c1, -m2a));
            float a1 = __builtin_amdgcn_exp2f(__builtin_fmaf(sa[nt][1], c1, -m2a));
            float a2 = __builtin_amdgcn_exp2f(__builtin_fmaf(sa[nt][2], c1, -m2a));
            float a3 = __builtin_amdgcn_exp2f(__builtin_fmaf(sa[nt][3], c1, -m2a));
            rsa += (a0 + a1) + (a2 + a3);
            ushort4 pk;
            pk.x = f2b(a0); pk.y = f2b(a1); pk.z = f2b(a2); pk.w = f2b(a3);
            int c8 = (2 * nt + qh) ^ psw;
            *(ushort4*)&Ps[wave][l16][c8 * 8 + 4 * ql] = pk;
            float b0 = __builtin_amdgcn_exp2f(__builtin_fmaf(sb[nt][0], c1, -m2b));
            float b1 = __builtin_amdgcn_exp2f(__builtin_fmaf(sb[nt][1], c1, -m2b));
            float b2 = __builtin_amdgcn_exp2f(__builtin_fmaf(sb[nt][2], c1, -m2b));
            float b3 = __builtin_amdgcn_exp2f(__builtin_fmaf(sb[nt][3], c1, -m2b));
            rsb += (b0 + b1) + (b2 + b3);
            pk.x = f2b(b0); pk.y = f2b(b1); pk.z = f2b(b2); pk.w = f2b(b3);
            *(ushort4*)&Ps[wave][16 + l16][c8 * 8 + 4 * ql] = pk;
        }
        rsa += __shfl_xor(rsa, 16);
        rsa += __shfl_xor(rsa, 32);
        rsb += __shfl_xor(rsb, 16);
        rsb += __shfl_xor(rsb, 32);
        lsa = ala * lsa + rsa;
        lsb = alb * lsb + rsb;
        if (need) {
            float a0 = __shfl(ala, quad * 4 + 0), a1 = __shfl(ala, quad * 4 + 1);
            float a2 = __shfl(ala, quad * 4 + 2), a3 = __shfl(ala, quad * 4 + 3);
            float b0 = __shfl(alb, quad * 4 + 0), b1 = __shfl(alb, quad * 4 + 1);
            float b2 = __shfl(alb, quad * 4 + 2), b3 = __shfl(alb, quad * 4 + 3);
#pragma unroll
            for (int ot = 0; ot < 4; ot++) {
                oa[ot][0] *= a0; oa[ot][1] *= a1; oa[ot][2] *= a2; oa[ot][3] *= a3;
                ob[ot][0] *= b0; ob[ot][1] *= b1; ob[ot][2] *= b2; ob[ot][3] *= b3;
            }
        }

        // (3) O += P V : V fragments read ONCE, used for both q-groups
        __builtin_amdgcn_s_setprio(1);
#pragma unroll
        for (int kt = 0; kt < 2; kt++) {
            int pc = ((kt * 4 + quad) ^ psw) * 8;
            short8 pfA = *(const short8*)&Ps[wave][l16][pc];
            short8 pfB = *(const short8*)&Ps[wave][16 + l16][pc];
#pragma unroll
            for (int ot = 0; ot < 4; ot++) {
                short8 vf = *(const short8*)&Vls[cur][ot * 16 + l16][pc];
                oa[ot] = MFMA16(pfA, vf, oa[ot]);
                ob[ot] = MFMA16(pfB, vf, ob[ot]);
            }
        }
        __builtin_amdgcn_s_setprio(0);

        ASM_BAR();
        if (t < 30) {
            stage((t + 2) * 64, cur);
            asm volatile("s_waitcnt vmcnt(4)" ::: "memory");
        } else {
            asm volatile("s_waitcnt vmcnt(0)" ::: "memory");
        }
        ASM_BAR();
        cur ^= 1;
    }

    // epilogue: normalize both groups, merge heads into [B][S][512]
    float la0 = __shfl(lsa, quad * 4 + 0), la1 = __shfl(lsa, quad * 4 + 1);
    float la2 = __shfl(lsa, quad * 4 + 2), la3 = __shfl(lsa, quad * 4 + 3);
    float lb0 = __shfl(lsb, quad * 4 + 0), lb1 = __shfl(lsb, quad * 4 + 1);
    float lb2 = __shfl(lsb, quad * 4 + 2), lb3 = __shfl(lsb, quad * 4 + 3);
    float ia0 = __builtin_amdgcn_rcpf(la0), ia1 = __builtin_amdgcn_rcpf(la1);
    float ia2 = __builtin_amdgcn_rcpf(la2), ia3 = __builtin_amdgcn_rcpf(la3);
    float ib0 = __builtin_amdgcn_rcpf(lb0), ib1 = __builtin_amdgcn_rcpf(lb1);
    float ib2 = __builtin_amdgcn_rcpf(lb2), ib3 = __builtin_amdgcn_rcpf(lb3);
    int srow0 = qt * 128 + wave * 32 + quad * 4;
#pragma unroll
    for (int ot = 0; ot < 4; ot++) {
        size_t base = ((size_t)bb * S_ + srow0) * D_ + hh * DP_ + ot * 16 + l16;
        ctx[base]          = f2b(oa[ot][0] * ia0);
        ctx[base + D_]     = f2b(oa[ot][1] * ia1);
        ctx[base + 2 * D_] = f2b(oa[ot][2] * ia2);
        ctx[base + 3 * D_] = f2b(oa[ot][3] * ia3);
        size_t baseB = base + (size_t)16 * D_;
        ctx[baseB]          = f2b(ob[ot][0] * ib0);
        ctx[baseB + D_]     = f2b(ob[ot][1] * ib1);
        ctx[baseB + 2 * D_] = f2b(ob[ot][2] * ib2);
        ctx[baseB + 3 * D_] = f2b(ob[ot][3] * ib3);
    }
}

// ---------------- output projection GEMM -> fp32 scratch (double-buffered, 8 K-tiles) ----------------
__global__ __launch_bounds__(256, 2)
void gemm_proj(const unsigned short* __restrict__ A,   // ctx [8192][512] bf16
               const unsigned short* __restrict__ Bt,  // Wo^T [512][512] bf16
               float* __restrict__ outf) {             // [8192][512] fp32
    int m0 = blockIdx.x * 128, n0 = blockIdx.y * 128;
    int tid = threadIdx.x;
    int wave = tid >> 6, lane = tid & 63, l16 = lane & 15, quad = lane >> 4;
    int wm = (wave >> 1) * 64, wn = (wave & 1) * 64;

    __shared__ __align__(16) unsigned short SM[32768];

    const int psw = l16 & 7;
    const int drow = lane >> 3;
    const int dsw = (lane & 7) ^ drow;

    const unsigned short* Abase = A + (size_t)m0 * D_;
    const unsigned short* Bbase = Bt + (size_t)n0 * D_;

    auto stage = [&](int t, int b) {
        int k0 = t * 64;
        unsigned short* As = SM + b * 16384;
        unsigned short* Bs = SM + b * 16384 + 8192;
#pragma unroll
        for (int j = 0; j < 4; j++) {
            int r8 = wave * 32 + j * 8;
            gload_lds16(Abase + (size_t)(r8 + drow) * D_ + k0 + dsw * 8, As + r8 * 64);
            gload_lds16(Bbase + (size_t)(r8 + drow) * D_ + k0 + dsw * 8, Bs + r8 * 64);
        }
    };

    f32x4 acc[4][4];   // [nt][mt]
    const f32x4 zf = {0.f, 0.f, 0.f, 0.f};
#pragma unroll
    for (int i = 0; i < 4; i++)
#pragma unroll
        for (int j = 0; j < 4; j++) acc[i][j] = zf;

    stage(0, 0);
    stage(1, 1);
    asm volatile("s_waitcnt vmcnt(8)" ::: "memory");
    ASM_BAR();

    for (int t = 0; t < 8; t++) {      // 8 x BK=64 = full K=512 (R13 bug: was 4)
        int b = t & 1;
        const unsigned short* As = SM + b * 16384;
        const unsigned short* Bs = SM + b * 16384 + 8192;
#pragma unroll
        for (int h = 0; h < 2; h++) {
            short8 af[4], bf[4];
#pragma unroll
            for (int mt = 0; mt < 4; mt++)
                af[mt] = *(const short8*)(As + (wm + mt * 16 + l16) * 64 + ((h * 4 + quad) ^ psw) * 8);
#pragma unroll
            for (int nt = 0; nt < 4; nt++)
                bf[nt] = *(const short8*)(Bs + (wn + nt * 16 + l16) * 64 + ((h * 4 + quad) ^ psw) * 8);
#pragma unroll
            for (int nt = 0; nt < 4; nt++)
#pragma unroll
                for (int mt = 0; mt < 4; mt++)
                    acc[nt][mt] = MFMA16(bf[nt], af[mt], acc[nt][mt]);   // C^T
        }
        if (t < 7) {
            ASM_BAR();
            if (t < 6) {
                stage(t + 2, b);
                asm volatile("s_waitcnt vmcnt(8)" ::: "memory");
            } else {
                asm volatile("s_waitcnt vmcnt(0)" ::: "memory");
            }
            ASM_BAR();
        }
    }
    // epilogue: lane holds 4 consecutive n (fp32) -> direct 16B stores
#pragma unroll
    for (int nt = 0; nt < 4; nt++)
#pragma unroll
        for (int mt = 0; mt < 4; mt++) {
            int m = m0 + wm + mt * 16 + l16;
            int n = n0 + wn + nt * 16 + quad * 4;
            *(f32x4*)&outf[(size_t)m * D_ + n] = acc[nt][mt];
        }
}

// ---------------- bias + residual + LayerNorm: one row per wave, pure-shfl ----------------
__global__ __launch_bounds__(256, 8)
void ln_out(const float* __restrict__ tmp, const float* __restrict__ Xg,
            const float* __restrict__ bo, const float* __restrict__ gamma,
            const float* __restrict__ beta, float* __restrict__ outp) {
    int wave = threadIdx.x >> 6, lane = threadIdx.x & 63;
    int row = blockIdx.x * 4 + wave;
    const float4* t4 = (const float4*)(tmp + (size_t)row * D_);
    const float4* x4 = (const float4*)(Xg + (size_t)row * D_);
    const float4* b4 = (const float4*)bo;
    const float4* g4 = (const float4*)gamma;
    const float4* e4 = (const float4*)beta;
    float4* o4 = (float4*)(outp + (size_t)row * D_);

    float4 r[2];
    float sum = 0.f, sq = 0.f;
#pragma unroll
    for (int i = 0; i < 2; i++) {
        int c = lane + i * 64;
        float4 a = t4[c], x = x4[c], b = b4[c];
        r[i].x = a.x + x.x + b.x;
        r[i].y = a.y + x.y + b.y;
        r[i].z = a.z + x.z + b.z;
        r[i].w = a.w + x.w + b.w;
        sum += (r[i].x + r[i].y) + (r[i].z + r[i].w);
        sq += (r[i].x * r[i].x + r[i].y * r[i].y) + (r[i].z * r[i].z + r[i].w * r[i].w);
    }
#pragma unroll
    for (int off = 1; off < 64; off <<= 1) {
        sum += __shfl_xor(sum, off);
        sq += __shfl_xor(sq, off);
    }
    float mu = sum * (1.0f / D_);
    float var = sq * (1.0f / D_) - mu * mu;
    float rstd = rsqrtf(var + 1e-6f);
#pragma unroll
    for (int i = 0; i < 2; i++) {
        int c = lane + i * 64;
        float4 g = g4[c], e = e4[c];
        float4 o;
        o.x = (r[i].x - mu) * rstd * g.x + e.x;
        o.y = (r[i].y - mu) * rstd * g.y + e.y;
        o.z = (r[i].z - mu) * rstd * g.z + e.z;
        o.w = (r[i].w - mu) * rstd * g.w + e.w;
        o4[c] = o;
    }
}

extern "C" void kernel_launch(void* const* d_in, const int* in_sizes, int n_in,
                              void* d_out, int out_size, void* d_ws, size_t ws_size,
                              hipStream_t stream) {
    const float* x     = (const float*)d_in[0];
    const float* wq    = (const float*)d_in[1];
    const float* wk    = (const float*)d_in[2];
    const float* wv    = (const float*)d_in[3];
    const float* wo    = (const float*)d_in[4];
    const float* bo    = (const float*)d_in[5];
    const float* gamma = (const float*)d_in[6];
    const float* beta  = (const float*)d_in[7];
    float* out = (float*)d_out;

    // ws layout (bf16 elems unless noted), total 34 MB:
    //   [xb 8MB | wt 2MB | Q,K,Vt 24MB]
    //   ctx aliases xb (xb dead after the projection GEMMs). fp32 tmp aliases Q (dead after flash).
    unsigned short* xb  = (unsigned short*)d_ws;                    // 8192*512 bf16
    unsigned short* wt  = xb + (size_t)M_ * D_;                     // 4*512*512 bf16
    unsigned short* Q   = wt + 4 * D_ * D_;
    unsigned short* K   = Q + (size_t)M_ * D_;
    unsigned short* Vt  = K + (size_t)M_ * D_;                      // [B][512][2048]
    unsigned short* ctx = xb;                                       // alias: xb dead
    float* tmp = (float*)Q;                                         // alias: Q/K/Vt dead

    prep<<<dim3(4096 + 256), 256, 0, stream>>>(x, xb, wq, wk, wv, wo, wt);
    gemm_qkvv<<<dim3(64, 4, 3), 256, 0, stream>>>(xb, wt, Q, Vt);
    flash_attn<<<dim3(512), 256, 0, stream>>>(Q, K, Vt, ctx);
    gemm_proj<<<dim3(64, 4), 256, 0, stream>>>(ctx, wt + 3 * (size_t)D_ * D_, tmp);
    ln_out<<<dim3(2048), 256, 0, stream>>>(tmp, x, bo, gamma, beta, out);
}

// Round 15
// 174.867 us; speedup vs baseline: 1.0918x; 1.0188x over previous
//
#include <hip/hip_runtime.h>
#include <hip/hip_bf16.h>

typedef __attribute__((ext_vector_type(8))) short short8;
typedef __attribute__((ext_vector_type(4))) float f32x4;

constexpr int B_ = 4, S_ = 2048, D_ = 512, H_ = 8, DP_ = 64;
constexpr int M_ = B_ * S_;  // 8192 rows

__device__ __forceinline__ unsigned short f2b(float f) {
    __hip_bfloat16 h = __float2bfloat16(f);
    return *reinterpret_cast<unsigned short*>(&h);
}

__device__ __forceinline__ void gload_lds16(const unsigned short* g, unsigned short* l) {
    __builtin_amdgcn_global_load_lds((const __attribute__((address_space(1))) void*)g,
                                     (__attribute__((address_space(3))) void*)l, 16, 0, 0);
}

#define MFMA16(a, b, c) __builtin_amdgcn_mfma_f32_16x16x32_bf16((a), (b), (c), 0, 0, 0)
#define ASM_BAR() asm volatile("s_barrier" ::: "memory")

// ---------------- prep: convert_x (blocks 0..4095) U transpose_w (blocks 4096..4351) ----
__global__ __launch_bounds__(256)
void prep(const float* __restrict__ x, unsigned short* __restrict__ xb,
          const float* __restrict__ w0, const float* __restrict__ w1,
          const float* __restrict__ w2, const float* __restrict__ w3,
          unsigned short* __restrict__ outw) {
    __shared__ float t[64][65];
    int bx = blockIdx.x;
    int tid = threadIdx.x;
    if (bx < 4096) {
        int i = bx * 256 + tid;   // one float4 per thread
        float4 v = ((const float4*)x)[i];
        ushort4 o;
        o.x = f2b(v.x); o.y = f2b(v.y); o.z = f2b(v.z); o.w = f2b(v.w);
        ((ushort4*)xb)[i] = o;
        return;
    }
    int b = bx - 4096;            // 256 transpose blocks
    int z = b >> 6, r = b & 63;
    int k0 = (r >> 3) * 64, n0 = (r & 7) * 64;
    const float* in = (z == 0) ? w0 : (z == 1) ? w1 : (z == 2) ? w2 : w3;
    unsigned short* out = outw + (size_t)z * D_ * D_;
    int tx = tid & 63, ty = tid >> 6;
#pragma unroll
    for (int i = 0; i < 16; i++) {
        int rr = ty * 16 + i;
        t[rr][tx] = in[(size_t)(k0 + rr) * D_ + n0 + tx];
    }
    __syncthreads();
#pragma unroll
    for (int i = 0; i < 16; i++) {
        int rr = ty * 16 + i;
        out[(size_t)(n0 + rr) * D_ + k0 + tx] = f2b(t[tx][rr]);
    }
}

// ======== merged projection GEMM: z=0 -> Q, z=1 -> K, z=2 -> V^T (unchanged R14) ========
__global__ __launch_bounds__(256, 2)
void gemm_qkvv(const unsigned short* __restrict__ X,
               const unsigned short* __restrict__ Wt,   // [3][512][512] transposed bf16
               unsigned short* __restrict__ QKV,        // [2][B][H][S][64]
               unsigned short* __restrict__ Vt) {       // [B][D][S]
    int z = blockIdx.z;
    int tid = threadIdx.x;
    int wave = tid >> 6, lane = tid & 63, l16 = lane & 15, quad = lane >> 4;
    int wm = (wave >> 1) * 64, wn = (wave & 1) * 64;

    int m0, n0, bb = 0;
    const unsigned short *Abase, *Bbase;
    if (z < 2) {
        m0 = blockIdx.x * 128; n0 = blockIdx.y * 128;
        Abase = X + (size_t)m0 * D_;
        Bbase = Wt + (size_t)z * D_ * D_ + (size_t)n0 * D_;
    } else {
        int idx = blockIdx.y * 64 + blockIdx.x;
        bb = idx >> 6;
        int r = idx & 63;
        m0 = (r & 3) * 128;
        n0 = (r >> 2) * 128;
        Abase = Wt + 2 * (size_t)D_ * D_ + (size_t)m0 * D_;
        Bbase = X + ((size_t)bb * S_ + n0) * D_;
    }

    __shared__ __align__(16) unsigned short SM[32768];
    unsigned short (*Cs)[136] = reinterpret_cast<unsigned short(*)[136]>(SM);

    const int psw = l16 & 7;
    const int drow = lane >> 3;
    const int dsw = (lane & 7) ^ drow;

    auto stage = [&](int t, int b) {
        int k0 = t * 64;
        unsigned short* As = SM + b * 16384;
        unsigned short* Bs = SM + b * 16384 + 8192;
#pragma unroll
        for (int j = 0; j < 4; j++) {
            int r8 = wave * 32 + j * 8;
            gload_lds16(Abase + (size_t)(r8 + drow) * D_ + k0 + dsw * 8, As + r8 * 64);
            gload_lds16(Bbase + (size_t)(r8 + drow) * D_ + k0 + dsw * 8, Bs + r8 * 64);
        }
    };

    f32x4 acc[4][4];   // [nt][mt]  (C^T)
    const f32x4 zf = {0.f, 0.f, 0.f, 0.f};
#pragma unroll
    for (int i = 0; i < 4; i++)
#pragma unroll
        for (int j = 0; j < 4; j++) acc[i][j] = zf;

    stage(0, 0);
    stage(1, 1);
    asm volatile("s_waitcnt vmcnt(8)" ::: "memory");
    ASM_BAR();

    for (int t = 0; t < 8; t++) {
        int b = t & 1;
        const unsigned short* As = SM + b * 16384;
        const unsigned short* Bs = SM + b * 16384 + 8192;
#pragma unroll
        for (int h = 0; h < 2; h++) {
            short8 af[4], bf[4];
#pragma unroll
            for (int mt = 0; mt < 4; mt++)
                af[mt] = *(const short8*)(As + (wm + mt * 16 + l16) * 64 + ((h * 4 + quad) ^ psw) * 8);
#pragma unroll
            for (int nt = 0; nt < 4; nt++)
                bf[nt] = *(const short8*)(Bs + (wn + nt * 16 + l16) * 64 + ((h * 4 + quad) ^ psw) * 8);
#pragma unroll
            for (int nt = 0; nt < 4; nt++)
#pragma unroll
                for (int mt = 0; mt < 4; mt++)
                    acc[nt][mt] = MFMA16(bf[nt], af[mt], acc[nt][mt]);   // C^T
        }
        if (t < 7) {
            ASM_BAR();
            if (t < 6) {
                stage(t + 2, b);
                asm volatile("s_waitcnt vmcnt(8)" ::: "memory");
            } else {
                asm volatile("s_waitcnt vmcnt(0)" ::: "memory");
            }
            ASM_BAR();
        }
    }
    __syncthreads();
#pragma unroll
    for (int nt = 0; nt < 4; nt++)
#pragma unroll
        for (int mt = 0; mt < 4; mt++) {
            ushort4 pk;
            pk.x = f2b(acc[nt][mt][0]); pk.y = f2b(acc[nt][mt][1]);
            pk.z = f2b(acc[nt][mt][2]); pk.w = f2b(acc[nt][mt][3]);
            *(ushort4*)&Cs[wm + mt * 16 + l16][wn + nt * 16 + quad * 4] = pk;
        }
    __syncthreads();
    if (z < 2) {
        unsigned short* out = QKV + (size_t)z * M_ * D_;
#pragma unroll
        for (int i = 0; i < 8; i++) {
            int c = tid + i * 256;
            int ml = c >> 4, nch = c & 15;
            int m = m0 + ml, n = n0 + nch * 8;
            int b2 = m >> 11, ss = m & 2047, hh = n >> 6, dd = n & 63;
            *(short8*)(out + ((((size_t)b2 * H_ + hh) * S_ + ss) * DP_ + dd)) =
                *(const short8*)&Cs[ml][nch * 8];
        }
    } else {
#pragma unroll
        for (int i = 0; i < 8; i++) {
            int c = tid + i * 256;
            int ml = c >> 4, nch = c & 15;
            *(short8*)(Vt + ((size_t)bb * D_ + m0 + ml) * S_ + n0 + nch * 8) =
                *(const short8*)&Cs[ml][nch * 8];
        }
    }
}

// ---------------- flash attention: KVBLK=128, 16 iters (halved barrier count) ----------------
// 512 blocks x 4 waves x 32 q-rows (unchanged); each iter stages+consumes 128 keys.
// Ps (64-wide, per-wave private) reused per 64-key half -> no extra barriers.
// LDS 80KB -> 2 blocks/CU (same residency as R11's 48KB config).
__global__ __launch_bounds__(256, 2)
void flash_attn(const unsigned short* __restrict__ Qg, const unsigned short* __restrict__ Kg,
                const unsigned short* __restrict__ Vt, unsigned short* __restrict__ ctx) {
    int bid0 = blockIdx.x;
    int bid = (bid0 & 7) * 64 + (bid0 >> 3);   // XCD swizzle (512 = 8*64, bijective)
    int qt = bid & 15, hh = (bid >> 4) & 7, bb = bid >> 7;
    int tid = threadIdx.x;
    int wave = tid >> 6, lane = tid & 63, l16 = lane & 15, quad = lane >> 4;
    int qh = quad >> 1, ql = quad & 1;

    size_t bh = ((size_t)bb * H_ + hh) * S_ * DP_;
    const unsigned short* Qb = Qg + bh;
    const unsigned short* Kb = Kg + bh;
    const unsigned short* Vb = Vt + bh;   // V^T head slice: 64 rows (d), 2048 cols (s)

    __shared__ __align__(16) unsigned short Kls[2][128][64];  // [buf][key s][d]   32KB
    __shared__ __align__(16) unsigned short Vls[2][64][128];  // [buf][d][key s]   32KB
    __shared__ __align__(16) unsigned short Ps[4][32][64];    // per-wave P        16KB

    const int psw = l16 & 7;
    const int drowK = (lane >> 3) & 7;
    const int lcK = (lane & 7) ^ drowK;          // K-DMA inverse-swizzled source chunk
    const int dvo = lane >> 4;                   // V-DMA row-within-4-group

    // Q: 32 rows per wave, two 16-row groups A/B
    short8 qa0, qa1, qb0, qb1;
    {
        const unsigned short* qp = Qb + (size_t)(qt * 128 + wave * 32 + l16) * DP_ + quad * 8;
        qa0 = *(const short8*)qp;
        qa1 = *(const short8*)(qp + 32);
        qb0 = *(const short8*)(qp + 16 * DP_);
        qb1 = *(const short8*)(qp + 16 * DP_ + 32);
    }

    // stage 128-key tile: per wave 4 K-gloads (8 rows each) + 4 V-gloads (4 rows each)
    auto stage = [&](int kv, int b) {
#pragma unroll
        for (int j = 0; j < 4; j++) {
            int r8 = (wave * 4 + j) * 8;
            gload_lds16(Kb + (size_t)(kv + r8 + drowK) * DP_ + lcK * 8, &Kls[b][r8][0]);
        }
#pragma unroll
        for (int j = 0; j < 4; j++) {
            int r4 = (wave * 4 + j) * 4;
            int dv = r4 + dvo;
            int lcV = (lane & 15) ^ (dv & 7);
            gload_lds16(Vb + (size_t)dv * S_ + kv + lcV * 8, &Vls[b][r4][0]);
        }
    };

    stage(0, 0);
    stage(128, 1);
    asm volatile("s_waitcnt vmcnt(8)" ::: "memory");
    ASM_BAR();

    const f32x4 zf = {0.f, 0.f, 0.f, 0.f};
    f32x4 oa[4], ob[4];
#pragma unroll
    for (int i = 0; i < 4; i++) { oa[i] = zf; ob[i] = zf; }
    float m2a = -1e30f, m2b = -1e30f;
    float lsa = 0.f, lsb = 0.f;
    constexpr float c1 = 0.125f * 1.44269504088896f;  // (1/sqrt(64)) * log2(e)

    int cur = 0;
    for (int t = 0; t < 16; t++) {
        // (1) S^T = K Q^T over 128 keys, both q-groups; K fragments read once
        __builtin_amdgcn_s_setprio(1);
        f32x4 sa[8], sb[8];
#pragma unroll
        for (int nt = 0; nt < 8; nt++) {
            const unsigned short* kr = &Kls[cur][nt * 16 + l16][0];
            short8 kf0 = *(const short8*)(kr + ((quad ^ psw) * 8));
            short8 kf1 = *(const short8*)(kr + (((quad ^ 4) ^ psw) * 8));
            f32x4 s = zf;
            s = MFMA16(kf0, qa0, s);
            s = MFMA16(kf1, qa1, s);
            sa[nt] = s;
            s = zf;
            s = MFMA16(kf0, qb0, s);
            s = MFMA16(kf1, qb1, s);
            sb[nt] = s;
        }
        __builtin_amdgcn_s_setprio(0);

        // (2) defer-max online softmax over 128 keys, two lane-local rows
        float ga, gb;
        {
            float ta[8], tb[8];
#pragma unroll
            for (int nt = 0; nt < 8; nt++) {
                ta[nt] = fmaxf(fmaxf(sa[nt][0], sa[nt][1]), fmaxf(sa[nt][2], sa[nt][3]));
                tb[nt] = fmaxf(fmaxf(sb[nt][0], sb[nt][1]), fmaxf(sb[nt][2], sb[nt][3]));
            }
            ga = fmaxf(fmaxf(fmaxf(ta[0], ta[1]), fmaxf(ta[2], ta[3])),
                       fmaxf(fmaxf(ta[4], ta[5]), fmaxf(ta[6], ta[7])));
            gb = fmaxf(fmaxf(fmaxf(tb[0], tb[1]), fmaxf(tb[2], tb[3])),
                       fmaxf(fmaxf(tb[4], tb[5]), fmaxf(tb[6], tb[7])));
        }
        ga = fmaxf(ga, __shfl_xor(ga, 16));
        ga = fmaxf(ga, __shfl_xor(ga, 32));
        gb = fmaxf(gb, __shfl_xor(gb, 16));
        gb = fmaxf(gb, __shfl_xor(gb, 32));
        ga *= c1; gb *= c1;
        float ala = 1.0f, alb = 1.0f;
        bool need = !__all((ga <= m2a + 8.0f) && (gb <= m2b + 8.0f));
        if (need) {
            float na = fmaxf(m2a, ga), nb = fmaxf(m2b, gb);
            ala = __builtin_amdgcn_exp2f(m2a - na);
            alb = __builtin_amdgcn_exp2f(m2b - nb);
            m2a = na; m2b = nb;
        }
        if (need) {
            float a0 = __shfl(ala, quad * 4 + 0), a1 = __shfl(ala, quad * 4 + 1);
            float a2 = __shfl(ala, quad * 4 + 2), a3 = __shfl(ala, quad * 4 + 3);
            float b0 = __shfl(alb, quad * 4 + 0), b1 = __shfl(alb, quad * 4 + 1);
            float b2 = __shfl(alb, quad * 4 + 2), b3 = __shfl(alb, quad * 4 + 3);
#pragma unroll
            for (int ot = 0; ot < 4; ot++) {
                oa[ot][0] *= a0; oa[ot][1] *= a1; oa[ot][2] *= a2; oa[ot][3] *= a3;
                ob[ot][0] *= b0; ob[ot][1] *= b1; ob[ot][2] *= b2; ob[ot][3] *= b3;
            }
        }

        // (3) per 64-key half: P -> Ps (per-wave, no barrier), then O += P V
        float rsa = 0.f, rsb = 0.f;
#pragma unroll
        for (int h = 0; h < 2; h++) {
#pragma unroll
            for (int ntl = 0; ntl < 4; ntl++) {
                int nt = h * 4 + ntl;
                float a0 = __builtin_amdgcn_exp2f(__builtin_fmaf(sa[nt][0], c1, -m2a));
                float a1 = __builtin_amdgcn_exp2f(__builtin_fmaf(sa[nt][1], c1, -m2a));
                float a2 = __builtin_amdgcn_exp2f(__builtin_fmaf(sa[nt][2], c1, -m2a));
                float a3 = __builtin_amdgcn_exp2f(__builtin_fmaf(sa[nt][3], c1, -m2a));
                rsa += (a0 + a1) + (a2 + a3);
                ushort4 pk;
                pk.x = f2b(a0); pk.y = f2b(a1); pk.z = f2b(a2); pk.w = f2b(a3);
                int c8 = (2 * ntl + qh) ^ psw;
                *(ushort4*)&Ps[wave][l16][c8 * 8 + 4 * ql] = pk;
                float b0 = __builtin_amdgcn_exp2f(__builtin_fmaf(sb[nt][0], c1, -m2b));
                float b1 = __builtin_amdgcn_exp2f(__builtin_fmaf(sb[nt][1], c1, -m2b));
                float b2 = __builtin_amdgcn_exp2f(__builtin_fmaf(sb[nt][2], c1, -m2b));
                float b3 = __builtin_amdgcn_exp2f(__builtin_fmaf(sb[nt][3], c1, -m2b));
                rsb += (b0 + b1) + (b2 + b3);
                pk.x = f2b(b0); pk.y = f2b(b1); pk.z = f2b(b2); pk.w = f2b(b3);
                *(ushort4*)&Ps[wave][16 + l16][c8 * 8 + 4 * ql] = pk;
            }
            __builtin_amdgcn_s_setprio(1);
#pragma unroll
            for (int kt = 0; kt < 2; kt++) {
                int pcl = (kt * 4 + quad) ^ psw;            // Ps chunk (local 64 keys)
                short8 pfA = *(const short8*)&Ps[wave][l16][pcl * 8];
                short8 pfB = *(const short8*)&Ps[wave][16 + l16][pcl * 8];
#pragma unroll
                for (int ot = 0; ot < 4; ot++) {
                    short8 vf = *(const short8*)&Vls[cur][ot * 16 + l16][(h * 8 + pcl) * 8];
                    oa[ot] = MFMA16(pfA, vf, oa[ot]);
                    ob[ot] = MFMA16(pfB, vf, ob[ot]);
                }
            }
            __builtin_amdgcn_s_setprio(0);
        }
        rsa += __shfl_xor(rsa, 16);
        rsa += __shfl_xor(rsa, 32);
        rsb += __shfl_xor(rsb, 16);
        rsb += __shfl_xor(rsb, 32);
        lsa = ala * lsa + rsa;
        lsb = alb * lsb + rsb;

        // (4) refill consumed buffer with tile t+2; wait tile t+1 only
        if (t < 15) {
            ASM_BAR();
            if (t < 14) {
                stage((t + 2) * 128, cur);
                asm volatile("s_waitcnt vmcnt(8)" ::: "memory");
            } else {
                asm volatile("s_waitcnt vmcnt(0)" ::: "memory");
            }
            ASM_BAR();
        }
        cur ^= 1;
    }

    // epilogue: normalize both groups, merge heads into [B][S][512]
    float la0 = __shfl(lsa, quad * 4 + 0), la1 = __shfl(lsa, quad * 4 + 1);
    float la2 = __shfl(lsa, quad * 4 + 2), la3 = __shfl(lsa, quad * 4 + 3);
    float lb0 = __shfl(lsb, quad * 4 + 0), lb1 = __shfl(lsb, quad * 4 + 1);
    float lb2 = __shfl(lsb, quad * 4 + 2), lb3 = __shfl(lsb, quad * 4 + 3);
    float ia0 = __builtin_amdgcn_rcpf(la0), ia1 = __builtin_amdgcn_rcpf(la1);
    float ia2 = __builtin_amdgcn_rcpf(la2), ia3 = __builtin_amdgcn_rcpf(la3);
    float ib0 = __builtin_amdgcn_rcpf(lb0), ib1 = __builtin_amdgcn_rcpf(lb1);
    float ib2 = __builtin_amdgcn_rcpf(lb2), ib3 = __builtin_amdgcn_rcpf(lb3);
    int srow0 = qt * 128 + wave * 32 + quad * 4;
#pragma unroll
    for (int ot = 0; ot < 4; ot++) {
        size_t base = ((size_t)bb * S_ + srow0) * D_ + hh * DP_ + ot * 16 + l16;
        ctx[base]          = f2b(oa[ot][0] * ia0);
        ctx[base + D_]     = f2b(oa[ot][1] * ia1);
        ctx[base + 2 * D_] = f2b(oa[ot][2] * ia2);
        ctx[base + 3 * D_] = f2b(oa[ot][3] * ia3);
        size_t baseB = base + (size_t)16 * D_;
        ctx[baseB]          = f2b(ob[ot][0] * ib0);
        ctx[baseB + D_]     = f2b(ob[ot][1] * ib1);
        ctx[baseB + 2 * D_] = f2b(ob[ot][2] * ib2);
        ctx[baseB + 3 * D_] = f2b(ob[ot][3] * ib3);
    }
}

// ---------------- output projection GEMM -> fp32 scratch (unchanged R14) ----------------
__global__ __launch_bounds__(256, 2)
void gemm_proj(const unsigned short* __restrict__ A,   // ctx [8192][512] bf16
               const unsigned short* __restrict__ Bt,  // Wo^T [512][512] bf16
               float* __restrict__ outf) {             // [8192][512] fp32
    int m0 = blockIdx.x * 128, n0 = blockIdx.y * 128;
    int tid = threadIdx.x;
    int wave = tid >> 6, lane = tid & 63, l16 = lane & 15, quad = lane >> 4;
    int wm = (wave >> 1) * 64, wn = (wave & 1) * 64;

    __shared__ __align__(16) unsigned short SM[32768];

    const int psw = l16 & 7;
    const int drow = lane >> 3;
    const int dsw = (lane & 7) ^ drow;

    const unsigned short* Abase = A + (size_t)m0 * D_;
    const unsigned short* Bbase = Bt + (size_t)n0 * D_;

    auto stage = [&](int t, int b) {
        int k0 = t * 64;
        unsigned short* As = SM + b * 16384;
        unsigned short* Bs = SM + b * 16384 + 8192;
#pragma unroll
        for (int j = 0; j < 4; j++) {
            int r8 = wave * 32 + j * 8;
            gload_lds16(Abase + (size_t)(r8 + drow) * D_ + k0 + dsw * 8, As + r8 * 64);
            gload_lds16(Bbase + (size_t)(r8 + drow) * D_ + k0 + dsw * 8, Bs + r8 * 64);
        }
    };

    f32x4 acc[4][4];   // [nt][mt]
    const f32x4 zf = {0.f, 0.f, 0.f, 0.f};
#pragma unroll
    for (int i = 0; i < 4; i++)
#pragma unroll
        for (int j = 0; j < 4; j++) acc[i][j] = zf;

    stage(0, 0);
    stage(1, 1);
    asm volatile("s_waitcnt vmcnt(8)" ::: "memory");
    ASM_BAR();

    for (int t = 0; t < 8; t++) {
        int b = t & 1;
        const unsigned short* As = SM + b * 16384;
        const unsigned short* Bs = SM + b * 16384 + 8192;
#pragma unroll
        for (int h = 0; h < 2; h++) {
            short8 af[4], bf[4];
#pragma unroll
            for (int mt = 0; mt < 4; mt++)
                af[mt] = *(const short8*)(As + (wm + mt * 16 + l16) * 64 + ((h * 4 + quad) ^ psw) * 8);
#pragma unroll
            for (int nt = 0; nt < 4; nt++)
                bf[nt] = *(const short8*)(Bs + (wn + nt * 16 + l16) * 64 + ((h * 4 + quad) ^ psw) * 8);
#pragma unroll
            for (int nt = 0; nt < 4; nt++)
#pragma unroll
                for (int mt = 0; mt < 4; mt++)
                    acc[nt][mt] = MFMA16(bf[nt], af[mt], acc[nt][mt]);   // C^T
        }
        if (t < 7) {
            ASM_BAR();
            if (t < 6) {
                stage(t + 2, b);
                asm volatile("s_waitcnt vmcnt(8)" ::: "memory");
            } else {
                asm volatile("s_waitcnt vmcnt(0)" ::: "memory");
            }
            ASM_BAR();
        }
    }
#pragma unroll
    for (int nt = 0; nt < 4; nt++)
#pragma unroll
        for (int mt = 0; mt < 4; mt++) {
            int m = m0 + wm + mt * 16 + l16;
            int n = n0 + wn + nt * 16 + quad * 4;
            *(f32x4*)&outf[(size_t)m * D_ + n] = acc[nt][mt];
        }
}

// ---------------- bias + residual + LayerNorm: one row per wave, pure-shfl ----------------
__global__ __launch_bounds__(256, 8)
void ln_out(const float* __restrict__ tmp, const float* __restrict__ Xg,
            const float* __restrict__ bo, const float* __restrict__ gamma,
            const float* __restrict__ beta, float* __restrict__ outp) {
    int wave = threadIdx.x >> 6, lane = threadIdx.x & 63;
    int row = blockIdx.x * 4 + wave;
    const float4* t4 = (const float4*)(tmp + (size_t)row * D_);
    const float4* x4 = (const float4*)(Xg + (size_t)row * D_);
    const float4* b4 = (const float4*)bo;
    const float4* g4 = (const float4*)gamma;
    const float4* e4 = (const float4*)beta;
    float4* o4 = (float4*)(outp + (size_t)row * D_);

    float4 r[2];
    float sum = 0.f, sq = 0.f;
#pragma unroll
    for (int i = 0; i < 2; i++) {
        int c = lane + i * 64;
        float4 a = t4[c], x = x4[c], b = b4[c];
        r[i].x = a.x + x.x + b.x;
        r[i].y = a.y + x.y + b.y;
        r[i].z = a.z + x.z + b.z;
        r[i].w = a.w + x.w + b.w;
        sum += (r[i].x + r[i].y) + (r[i].z + r[i].w);
        sq += (r[i].x * r[i].x + r[i].y * r[i].y) + (r[i].z * r[i].z + r[i].w * r[i].w);
    }
#pragma unroll
    for (int off = 1; off < 64; off <<= 1) {
        sum += __shfl_xor(sum, off);
        sq += __shfl_xor(sq, off);
    }
    float mu = sum * (1.0f / D_);
    float var = sq * (1.0f / D_) - mu * mu;
    float rstd = rsqrtf(var + 1e-6f);
#pragma unroll
    for (int i = 0; i < 2; i++) {
        int c = lane + i * 64;
        float4 g = g4[c], e = e4[c];
        float4 o;
        o.x = (r[i].x - mu) * rstd * g.x + e.x;
        o.y = (r[i].y - mu) * rstd * g.y + e.y;
        o.z = (r[i].z - mu) * rstd * g.z + e.z;
        o.w = (r[i].w - mu) * rstd * g.w + e.w;
        o4[c] = o;
    }
}

extern "C" void kernel_launch(void* const* d_in, const int* in_sizes, int n_in,
                              void* d_out, int out_size, void* d_ws, size_t ws_size,
                              hipStream_t stream) {
    const float* x     = (const float*)d_in[0];
    const float* wq    = (const float*)d_in[1];
    const float* wk    = (const float*)d_in[2];
    const float* wv    = (const float*)d_in[3];
    const float* wo    = (const float*)d_in[4];
    const float* bo    = (const float*)d_in[5];
    const float* gamma = (const float*)d_in[6];
    const float* beta  = (const float*)d_in[7];
    float* out = (float*)d_out;

    // ws layout (bf16 elems unless noted), total 34 MB:
    //   [xb 8MB | wt 2MB | Q,K,Vt 24MB]
    //   ctx aliases xb (xb dead after the projection GEMMs). fp32 tmp aliases Q (dead after flash).
    unsigned short* xb  = (unsigned short*)d_ws;                    // 8192*512 bf16
    unsigned short* wt  = xb + (size_t)M_ * D_;                     // 4*512*512 bf16
    unsigned short* Q   = wt + 4 * D_ * D_;
    unsigned short* K   = Q + (size_t)M_ * D_;
    unsigned short* Vt  = K + (size_t)M_ * D_;                      // [B][512][2048]
    unsigned short* ctx = xb;                                       // alias: xb dead
    float* tmp = (float*)Q;                                         // alias: Q/K/Vt dead

    prep<<<dim3(4096 + 256), 256, 0, stream>>>(x, xb, wq, wk, wv, wo, wt);
    gemm_qkvv<<<dim3(64, 4, 3), 256, 0, stream>>>(xb, wt, Q, Vt);
    flash_attn<<<dim3(512), 256, 0, stream>>>(Q, K, Vt, ctx);
    gemm_proj<<<dim3(64, 4), 256, 0, stream>>>(ctx, wt + 3 * (size_t)D_ * D_, tmp);
    ln_out<<<dim3(2048), 256, 0, stream>>>(tmp, x, bo, gamma, beta, out);
}